// Round 9
// baseline (240.933 us; speedup 1.0000x reference)
//
#include <hip/hip_runtime.h>
#include <hip/hip_bf16.h>

typedef __attribute__((ext_vector_type(8))) short short8;
typedef __attribute__((ext_vector_type(4))) float f32x4;
typedef __attribute__((ext_vector_type(16))) float f32x16;

#define N_EMBED 2048
#define N_HEAD 16
#define BB 2
#define SS 2048
#define NTOK (BB*SS)          // 4096
#define HD2 192               // absorbed head dim: 128 latent + 64 rope
#define QSTR 3072             // q_all row stride = 16*192

__device__ __forceinline__ unsigned short f2bf(float f) {
    unsigned int b = __builtin_bit_cast(unsigned int, f);
    b += 0x7fffu + ((b >> 16) & 1u);
    return (unsigned short)(b >> 16);
}
__device__ __forceinline__ float bf2f(unsigned short u) {
    unsigned int b = ((unsigned int)u) << 16;
    return __builtin_bit_cast(float, b);
}

#define GLOAD_LDS16(gsrc, ldst) __builtin_amdgcn_global_load_lds( \
    (const __attribute__((address_space(1))) void*)(gsrc), \
    (__attribute__((address_space(3))) void*)(ldst), 16, 0, 0)

#define ROPE_COEF (-0.28782313662425575f)  // -ln(10000)/32

// ---------------- prep: layouts + bf16 copies + rope table ----------------
// [0,2560) WcatT | [2560,3072) Wq2T rope rows | [3072,3584) WqcB | [3584,4096) WukB
// [4096,5120) WuvB | [5120,6144) WoT transpose | [6144,6400) rope table
__global__ __launch_bounds__(256) void prep_kernel(
    const float* __restrict__ Wdkv, const float* __restrict__ Wdq, const float* __restrict__ Wkr,
    const float* __restrict__ Wqc, const float* __restrict__ Wqr,
    const float* __restrict__ Wuk, const float* __restrict__ Wuv, const float* __restrict__ Wo,
    unsigned short* __restrict__ WcatT, unsigned short* __restrict__ Wq2T,
    unsigned short* __restrict__ WqcB, unsigned short* __restrict__ WukB,
    unsigned short* __restrict__ WuvB, unsigned short* __restrict__ WoT,
    float2* __restrict__ rope_tab) {
    __shared__ float tile[64][65];
    const int bid = blockIdx.x, tid = threadIdx.x;
    if (bid < 2560) {                       // WcatT [320][2048]
        int i = bid * 256 + tid;
        int n = i >> 11, k = i & 2047;
        float v;
        if (n < 128)      v = Wdkv[k * 128 + n];
        else if (n < 256) v = Wdq[k * 128 + (n - 128)];
        else              v = Wkr[k * 64 + (n - 256)];
        WcatT[i] = f2bf(v);
    } else if (bid < 3072) {                // Wq2T rope rows: [h][64 jr][128 k]
        int i = (bid - 2560) * 256 + tid;
        int h = i >> 13, jr = (i >> 7) & 63, k = i & 127;
        Wq2T[((size_t)(h * HD2 + 128 + jr)) * 128 + k] = f2bf(Wqr[(h * 128 + k) * 64 + jr]);
    } else if (bid < 3584) {                // WqcB plain copy [16][128][64]
        int i = (bid - 3072) * 256 + tid;
        WqcB[i] = f2bf(Wqc[i]);
    } else if (bid < 4096) {                // WukB plain copy
        int i = (bid - 3584) * 256 + tid;
        WukB[i] = f2bf(Wuk[i]);
    } else if (bid < 5120) {                // WuvB plain copy [16][128][128]
        int i = (bid - 4096) * 256 + tid;
        WuvB[i] = f2bf(Wuv[i]);
    } else if (bid < 6144) {                // WoT [2048][2048] tiled transpose
        int tb = bid - 5120;
        const int k0 = (tb & 31) * 64, n0 = (tb >> 5) * 64;
        const int tr = tid >> 4, tc = (tid & 15) * 4;
#pragma unroll
        for (int it = 0; it < 4; ++it) {
            int r = it * 16 + tr;
            float4 v = *(const float4*)(Wo + (size_t)(k0 + r) * 2048 + n0 + tc);
            tile[r][tc] = v.x; tile[r][tc + 1] = v.y; tile[r][tc + 2] = v.z; tile[r][tc + 3] = v.w;
        }
        __syncthreads();
#pragma unroll
        for (int it = 0; it < 4; ++it) {
            int r = it * 16 + tr;
            ushort4 o;
            o.x = f2bf(tile[tc][r]); o.y = f2bf(tile[tc + 1][r]);
            o.z = f2bf(tile[tc + 2][r]); o.w = f2bf(tile[tc + 3][r]);
            *(ushort4*)(WoT + (size_t)(n0 + r) * 2048 + k0 + tc) = o;
        }
    } else {                                // rope table [SS][32]
        int i = (bid - 6144) * 256 + tid;
        int pos = i >> 5, j = i & 31;
        float freq = __expf(ROPE_COEF * (float)j);
        float a = (float)pos * freq;
        float s, c;
        __sincosf(a, &s, &c);
        rope_tab[i] = make_float2(c, s);
    }
}

// ---------------- W_qk[h] = W_qc[h] @ W_uk[h]^T -> Wq2T rows h*192+[0,128) ----------------
// 16 blocks; no LDS, A/B frags straight from global (L2-hot).
__global__ __launch_bounds__(256) void wqk_kernel(
    const unsigned short* __restrict__ WqcB,   // [16][128][64]
    const unsigned short* __restrict__ WukB,   // [16][128][64]
    unsigned short* __restrict__ Wq2T) {       // [3072][128]
    const int h = blockIdx.x;
    const int tid = threadIdx.x, wave = tid >> 6, lane = tid & 63;
    const int wr = wave >> 1, wc = wave & 1;
    const int lg = lane >> 4, lr = lane & 15;
    const unsigned short* A = WqcB + (size_t)h * 8192;
    const unsigned short* Bt = WukB + (size_t)h * 8192;
    f32x4 acc[4][4] = {};
#pragma unroll
    for (int kk = 0; kk < 2; ++kk) {
        short8 af[4], bfr[4];
#pragma unroll
        for (int i = 0; i < 4; i++) af[i] = *(const short8*)(A + (wr * 64 + i * 16 + lr) * 64 + kk * 32 + lg * 8);
#pragma unroll
        for (int j = 0; j < 4; j++) bfr[j] = *(const short8*)(Bt + (wc * 64 + j * 16 + lr) * 64 + kk * 32 + lg * 8);
#pragma unroll
        for (int i = 0; i < 4; i++)
#pragma unroll
            for (int j = 0; j < 4; j++)
                acc[i][j] = __builtin_amdgcn_mfma_f32_16x16x32_bf16(af[i], bfr[j], acc[i][j], 0, 0, 0);
    }
#pragma unroll
    for (int i = 0; i < 4; i++)
#pragma unroll
        for (int j = 0; j < 4; j++)
#pragma unroll
            for (int r = 0; r < 4; r++) {
                int row = wr * 64 + i * 16 + lg * 4 + r;   // k_in
                int col = wc * 64 + j * 16 + lr;           // latent k'
                Wq2T[((size_t)(h * HD2 + col)) * 128 + row] = f2bf(acc[i][j][r]);
            }
}

// ---------------- W_effT[e][h*128+dl] = sum_dh WuvB[h][dl][dh] * WoT[e][h*128+dh] ----------------
// grid (16 e-tiles, 16 h)
__global__ __launch_bounds__(256) void weff_kernel(
    const unsigned short* __restrict__ WoT,    // [2048][2048]
    const unsigned short* __restrict__ WuvB,   // [16][128][128]
    unsigned short* __restrict__ WeffT) {      // [2048][2048]
    constexpr int BK = 32;
    __shared__ __align__(16) unsigned short As[2][128][BK];
    __shared__ __align__(16) unsigned short Bs[2][128][BK];
    const int et = blockIdx.x, h = blockIdx.y;
    const int tid = threadIdx.x, wave = tid >> 6, lane = tid & 63;
    const int wr = wave >> 1, wc = wave & 1;
    const int lg = lane >> 4, lr = lane & 15;
    const unsigned short* A = WoT + (size_t)et * 128 * 2048 + h * 128;  // rows e, lda 2048
    const unsigned short* Bt = WuvB + (size_t)h * 16384;                // [128][128]

    f32x4 acc[4][4] = {};
    auto stage = [&](int k0, int buf) {
#pragma unroll
        for (int it = 0; it < 2; ++it) {
            int e = (tid + it * 256) * 8;
            GLOAD_LDS16(A + (size_t)(e >> 5) * 2048 + k0 + (e & 31), &As[buf][0][0] + e);
        }
#pragma unroll
        for (int it = 0; it < 2; ++it) {
            int e = (tid + it * 256) * 8;
            GLOAD_LDS16(Bt + (size_t)(e >> 5) * 128 + k0 + (e & 31), &Bs[buf][0][0] + e);
        }
    };
    stage(0, 0);
    __syncthreads();
    for (int t = 0; t < 4; ++t) {
        const int cur = t & 1;
        if (t + 1 < 4) stage((t + 1) * BK, cur ^ 1);
        short8 af[4], bfr[4];
#pragma unroll
        for (int i = 0; i < 4; i++) af[i] = *(const short8*)&As[cur][wr * 64 + i * 16 + lr][lg * 8];
#pragma unroll
        for (int j = 0; j < 4; j++) bfr[j] = *(const short8*)&Bs[cur][wc * 64 + j * 16 + lr][lg * 8];
#pragma unroll
        for (int i = 0; i < 4; i++)
#pragma unroll
            for (int j = 0; j < 4; j++)
                acc[i][j] = __builtin_amdgcn_mfma_f32_16x16x32_bf16(af[i], bfr[j], acc[i][j], 0, 0, 0);
        __syncthreads();
    }
#pragma unroll
    for (int i = 0; i < 4; i++)
#pragma unroll
        for (int j = 0; j < 4; j++)
#pragma unroll
            for (int r = 0; r < 4; r++) {
                int row = et * 128 + wr * 64 + i * 16 + lg * 4 + r;   // e
                int col = wc * 64 + j * 16 + lr;                      // dl
                WeffT[(size_t)row * 2048 + h * 128 + col] = f2bf(acc[i][j][r]);
            }
}

// ---------------- ckv_t[b][dl][s] = g1[b*SS+s][dl] (64x64 LDS transpose) ----------------
__global__ __launch_bounds__(256) void ckvt_kernel(
    const unsigned short* __restrict__ g1, unsigned short* __restrict__ ckv_t) {
    __shared__ unsigned short tile[64][65];
    const int s0 = blockIdx.x * 64, d0 = blockIdx.y * 64, b = blockIdx.z;
    const int tid = threadIdx.x;
    const int tr = tid >> 4, tc = (tid & 15) * 4;
#pragma unroll
    for (int it = 0; it < 4; ++it) {
        int r = it * 16 + tr;
        *(ushort4*)&tile[r][tc] = *(const ushort4*)(g1 + (size_t)(b * SS + s0 + r) * 320 + d0 + tc);
    }
    __syncthreads();
#pragma unroll
    for (int it = 0; it < 4; ++it) {
        int r = it * 16 + tr;
        ushort4 o;
        o.x = tile[tc][r]; o.y = tile[tc + 1][r]; o.z = tile[tc + 2][r]; o.w = tile[tc + 3][r];
        *(ushort4*)(ckv_t + ((size_t)b * 128 + d0 + r) * 2048 + s0 + tc) = o;
    }
}

// ---------------- fused rope ----------------
__global__ __launch_bounds__(256) void rope_all_kernel(
    unsigned short* __restrict__ g1, unsigned short* __restrict__ q,
    const float2* __restrict__ tab) {
    const int bid = blockIdx.x, tid = threadIdx.x;
    if (bid < 512) {                        // k_rope: NTOK*32
        int i = bid * 256 + tid;
        int j = i & 31, row = i >> 5;
        int pos = row & (SS - 1);
        float2 cs = tab[(pos << 5) | j];
        unsigned short* p = g1 + (size_t)row * 320 + 256 + 2 * j;
        float x0 = bf2f(p[0]), x1 = bf2f(p[1]);
        p[0] = f2bf(x0 * cs.x - x1 * cs.y);
        p[1] = f2bf(x0 * cs.y + x1 * cs.x);
    } else {                                // q_rope: NTOK*16*32
        int i = (bid - 512) * 256 + tid;
        int j = i & 31, h = (i >> 5) & 15, row = i >> 9;
        int pos = row & (SS - 1);
        float2 cs = tab[(pos << 5) | j];
        unsigned short* p = q + (size_t)row * QSTR + h * HD2 + 128 + 2 * j;
        float x0 = bf2f(p[0]), x1 = bf2f(p[1]);
        p[0] = f2bf(x0 * cs.x - x1 * cs.y);
        p[1] = f2bf(x0 * cs.y + x1 * cs.x);
    }
}

// ---------------- GEMM (2-phase dbuf): C[M,N] = A[M,K] * Bt[N,K]^T ----------------

__device__ __forceinline__ void store_c(float* p, float v) { *p = v; }
__device__ __forceinline__ void store_c(unsigned short* p, float v) { *p = f2bf(v); }

template <int BN, typename CT, bool SWZ>
__global__ __launch_bounds__(256) void gemm_bf16_kernel(
    const unsigned short* __restrict__ A, int lda,
    const unsigned short* __restrict__ Bt, int ldb,
    CT* __restrict__ C, int ldc,
    int M, int N, int K) {
    constexpr int BM = 128, BK = 32;
    __shared__ __align__(16) unsigned short As[2][BM][BK];
    __shared__ __align__(16) unsigned short Bs[2][BN][BK];
    constexpr int WN = BN / 2;
    constexpr int FM = 4, FN = WN / 16;
    const int tid = threadIdx.x, wave = tid >> 6, lane = tid & 63;
    const int wr = wave >> 1, wc = wave & 1;
    const int lg = lane >> 4, lr = lane & 15;
    int m0, n0;
    if (SWZ) {
        int id = blockIdx.y * gridDim.x + blockIdx.x;
        int tot = gridDim.x * gridDim.y;
        int swz = (id & 7) * (tot >> 3) + (id >> 3);
        n0 = (swz % gridDim.x) * BN;
        m0 = (swz / gridDim.x) * BM;
    } else {
        m0 = blockIdx.y * BM; n0 = blockIdx.x * BN;
    }

    f32x4 acc[FM][FN] = {};

    auto stage = [&](int k0, int buf) {
#pragma unroll
        for (int it = 0; it < (BM * BK) / 2048; ++it) {
            int e = (tid + it * 256) * 8;
            GLOAD_LDS16(A + (size_t)(m0 + (e >> 5)) * lda + k0 + (e & 31), &As[buf][0][0] + e);
        }
#pragma unroll
        for (int it = 0; it < (BN * BK) / 2048; ++it) {
            int e = (tid + it * 256) * 8;
            GLOAD_LDS16(Bt + (size_t)(n0 + (e >> 5)) * ldb + k0 + (e & 31), &Bs[buf][0][0] + e);
        }
    };

    const int nk = K / BK;
    stage(0, 0);
    __syncthreads();
    for (int t = 0; t < nk; ++t) {
        const int cur = t & 1;
        if (t + 1 < nk) stage((t + 1) * BK, cur ^ 1);
        short8 af[FM], bfr[FN];
#pragma unroll
        for (int i = 0; i < FM; i++) af[i] = *(const short8*)&As[cur][wr * 64 + i * 16 + lr][lg * 8];
#pragma unroll
        for (int j = 0; j < FN; j++) bfr[j] = *(const short8*)&Bs[cur][wc * WN + j * 16 + lr][lg * 8];
#pragma unroll
        for (int i = 0; i < FM; i++)
#pragma unroll
            for (int j = 0; j < FN; j++)
                acc[i][j] = __builtin_amdgcn_mfma_f32_16x16x32_bf16(af[i], bfr[j], acc[i][j], 0, 0, 0);
        __syncthreads();
    }
#pragma unroll
    for (int i = 0; i < FM; i++)
#pragma unroll
        for (int j = 0; j < FN; j++)
#pragma unroll
            for (int r = 0; r < 4; r++) {
                int row = m0 + wr * 64 + i * 16 + lg * 4 + r;
                int col = n0 + wc * WN + j * 16 + lr;
                store_c(&C[(size_t)row * ldc + col], acc[i][j][r]);
            }
}

// Latent GEMM with f32 A (conversion folded in)
__global__ __launch_bounds__(256) void gemm_lat_kernel(
    const float* __restrict__ A,               // [NTOK][2048] f32
    const unsigned short* __restrict__ Bt,     // WcatT [320][2048]
    unsigned short* __restrict__ C) {          // g1 [NTOK][320]
    constexpr int BM = 128, BN = 64, BK = 32, K = 2048;
    __shared__ __align__(16) unsigned short As[2][BM][BK];
    __shared__ __align__(16) unsigned short Bs[2][BN][BK];
    constexpr int WN = BN / 2, FM = 4, FN = WN / 16;
    const int tid = threadIdx.x, wave = tid >> 6, lane = tid & 63;
    const int wr = wave >> 1, wc = wave & 1;
    const int lg = lane >> 4, lr = lane & 15;
    const int m0 = blockIdx.y * BM, n0 = blockIdx.x * BN;

    f32x4 acc[FM][FN] = {};
    const int ar = (tid * 16) >> 5, ac = (tid * 16) & 31;

    float4 a4[4];
    auto loadA = [&](int k0) {
        const float* src = A + (size_t)(m0 + ar) * K + k0 + ac;
#pragma unroll
        for (int i = 0; i < 4; ++i) a4[i] = *(const float4*)(src + i * 4);
    };
    auto writeA = [&](int buf) {
        unsigned int pk[8];
        const float* f = (const float*)a4;
#pragma unroll
        for (int i = 0; i < 8; ++i)
            asm("v_cvt_pk_bf16_f32 %0, %1, %2" : "=v"(pk[i]) : "v"(f[2 * i]), "v"(f[2 * i + 1]));
        *(uint4*)&As[buf][ar][ac]     = make_uint4(pk[0], pk[1], pk[2], pk[3]);
        *(uint4*)&As[buf][ar][ac + 8] = make_uint4(pk[4], pk[5], pk[6], pk[7]);
    };
    auto stageB = [&](int k0, int buf) {
        int e = tid * 8;
        GLOAD_LDS16(Bt + (size_t)(n0 + (e >> 5)) * K + k0 + (e & 31), &Bs[buf][0][0] + e);
    };

    loadA(0); stageB(0, 0); writeA(0);
    __syncthreads();
    constexpr int nk = K / BK;
    for (int t = 0; t < nk; ++t) {
        const int cur = t & 1;
        if (t + 1 < nk) { loadA((t + 1) * BK); stageB((t + 1) * BK, cur ^ 1); }
        short8 af[FM], bfr[FN];
#pragma unroll
        for (int i = 0; i < FM; i++) af[i] = *(const short8*)&As[cur][wr * 64 + i * 16 + lr][lg * 8];
#pragma unroll
        for (int j = 0; j < FN; j++) bfr[j] = *(const short8*)&Bs[cur][wc * WN + j * 16 + lr][lg * 8];
#pragma unroll
        for (int i = 0; i < FM; i++)
#pragma unroll
            for (int j = 0; j < FN; j++)
                acc[i][j] = __builtin_amdgcn_mfma_f32_16x16x32_bf16(af[i], bfr[j], acc[i][j], 0, 0, 0);
        if (t + 1 < nk) writeA(cur ^ 1);
        __syncthreads();
    }
#pragma unroll
    for (int i = 0; i < FM; i++)
#pragma unroll
        for (int j = 0; j < FN; j++)
#pragma unroll
            for (int r = 0; r < 4; r++) {
                int row = m0 + wr * 64 + i * 16 + lg * 4 + r;
                int col = n0 + wc * WN + j * 16 + lr;
                C[(size_t)row * 320 + col] = f2bf(acc[i][j][r]);
            }
}

// ---------------- flash attention v8: absorbed (d=192), split-pair exact balance ----------------
// K = [c_kv(128) | k_rope(64)] shared by all heads (from g1); V = c_kv (from ckv_t).
// LDS: K dbuf [2][64][192] 48KB + V dbuf [2][128][64] 32KB = 80KB -> 2 blocks/CU.
__global__ __launch_bounds__(256, 2) void mla_attn_kernel(
    const unsigned short* __restrict__ q_all,   // [NTOK][3072]: per head [qtil(128)|qrope(64)]
    const unsigned short* __restrict__ g1,      // [NTOK][320]: ckv 0..127, roped k_r 256..319
    const unsigned short* __restrict__ ckv_t,   // [2][128][2048]
    unsigned short* __restrict__ attn_out,      // [NTOK][2048] (o_lat, latent dims)
    float* __restrict__ partO,                  // [256 pair][2 side][128 q][128 d]
    float* __restrict__ partL,
    float* __restrict__ partM) {
    __shared__ __align__(16) char smem[81920];
    auto Ks = (unsigned short (*)[64][192])smem;             // [2][64][192], chunk-swizzled
    auto Vs = (unsigned short (*)[128][64])(smem + 49152);   // [2][128][64], chunk-swizzled

    const int id = blockIdx.x;
    const int xcd = id & 7, loc = id >> 3;
    const int bh = 4 * xcd + (loc >> 4);
    const int s2 = loc & 15;
    const bool roleA = s2 < 8;
    const int qb = roleA ? s2 : s2 - 8;
    const int hiqb = 15 - qb, xsp = 15 - 2 * qb;
    const int pairIdx = bh * 8 + qb;
    const int b = bh >> 4, h = bh & 15;
    const int tid = threadIdx.x, wave = tid >> 6, lane = tid & 63;
    const int ql = lane & 31, hb = lane >> 5;
    const int kvB = b * SS;
    const float sc2 = 0.12751744f;   // (1/sqrt(128)) * log2(e)
    const int xh = ql & 7;

    uint4 vreg[4];
    auto stageK = [&](int t, int bufi) {
        // LDS linear by slot cid; slot s of row r holds global chunk c = s ^ (r&7)
#pragma unroll
        for (int it = 0; it < 6; ++it) {
            int cid = tid + it * 256;
            int r = cid / 24, s = cid - r * 24;
            int c = s ^ (r & 7);
            int col = (c < 16) ? c * 8 : 256 + (c - 16) * 8;
            GLOAD_LDS16(g1 + (size_t)(kvB + t * 64 + r) * 320 + col,
                        &Ks[bufi][0][0] + cid * 8);
        }
    };
    auto loadV = [&](int t) {
#pragma unroll
        for (int it = 0; it < 4; ++it) {
            int e = tid * 8 + it * 2048;
            vreg[it] = *(const uint4*)(ckv_t + ((size_t)b * 128 + (e >> 6)) * 2048 + t * 64 + (e & 63));
        }
    };
    auto writeV = [&](int bufi) {
#pragma unroll
        for (int it = 0; it < 4; ++it) {
            int e = tid * 8 + it * 2048;
            int d = e >> 6, j = (e & 63) >> 3;
            *(uint4*)&Vs[bufi][d][(j ^ (d & 7)) * 8] = vreg[it];
        }
    };

    auto run = [&](int q0, int t0, int cnt, bool direct, int side) {
        __syncthreads();   // fence prior smem use before restaging
        const int q0w = q0 + wave * 32;
        const int qg = q0w + ql;

        short8 qf[12];
        {
            const unsigned short* qp = q_all + (size_t)(kvB + qg) * QSTR + h * HD2 + hb * 8;
#pragma unroll
            for (int ss = 0; ss < 12; ++ss) qf[ss] = *(const short8*)(qp + 16 * ss);
        }
        f32x16 o[4] = {};
        float m_raw = -3e38f, mb = 0.f, l_r = 0.f;

        stageK(t0, 0);
        loadV(t0);
        writeV(0);
        __syncthreads();

        for (int tt = 0; tt < cnt; ++tt) {
            const int t = t0 + tt;
            const int cur = tt & 1;
            if (tt + 1 < cnt) { stageK(t + 1, cur ^ 1); loadV(t + 1); }
            {
                f32x16 p0 = {}, p1 = {};
                __builtin_amdgcn_s_setprio(1);
#pragma unroll
                for (int ss = 0; ss < 12; ++ss) {
                    int pc = (((2 * ss + hb) ^ xh) << 3);
                    short8 k0 = *(const short8*)&Ks[cur][ql][pc];
                    short8 k1 = *(const short8*)&Ks[cur][32 + ql][pc];
                    p0 = __builtin_amdgcn_mfma_f32_32x32x16_bf16(k0, qf[ss], p0, 0, 0, 0);
                    p1 = __builtin_amdgcn_mfma_f32_32x32x16_bf16(k1, qf[ss], p1, 0, 0, 0);
                }
                __builtin_amdgcn_s_setprio(0);
                const int kv0 = t * 64;
                if (kv0 + 63 > q0w) {
#pragma unroll
                    for (int r = 0; r < 16; ++r) {
                        int kvg = kv0 + (r & 3) + 8 * (r >> 2) + 4 * hb;
                        if (kvg > qg) p0[r] = -3e38f;
                        if (kvg + 32 > qg) p1[r] = -3e38f;
                    }
                }
                float pm = -3e38f;
#pragma unroll
                for (int r = 0; r < 16; ++r) pm = fmaxf(pm, fmaxf(p0[r], p1[r]));
                pm = fmaxf(pm, __shfl_xor(pm, 32));
                if (__any(pm > m_raw + 64.f)) {   // defer-max (T13)
                    float mn = fmaxf(m_raw, pm);
                    float alpha = exp2f((m_raw - mn) * sc2);
                    m_raw = mn; mb = mn * sc2;
                    l_r *= alpha;
#pragma unroll
                    for (int dt = 0; dt < 4; ++dt)
#pragma unroll
                        for (int r = 0; r < 16; ++r) o[dt][r] *= alpha;
                }
                float ps = 0.f;
#pragma unroll
                for (int r = 0; r < 16; ++r) {
                    p0[r] = exp2f(__builtin_fmaf(p0[r], sc2, -mb));
                    p1[r] = exp2f(__builtin_fmaf(p1[r], sc2, -mb));
                    ps += p0[r] + p1[r];
                }
                l_r += ps;
                unsigned int pk0[8], pk1[8];
#pragma unroll
                for (int i = 0; i < 8; ++i) {
                    asm("v_cvt_pk_bf16_f32 %0, %1, %2" : "=v"(pk0[i]) : "v"(p0[2 * i]), "v"(p0[2 * i + 1]));
                    asm("v_cvt_pk_bf16_f32 %0, %1, %2" : "=v"(pk1[i]) : "v"(p1[2 * i]), "v"(p1[2 * i + 1]));
                }
                uint4 bfr[4];
#pragma unroll
                for (int sg = 0; sg < 2; ++sg) {
                    unsigned int x0 = pk0[4 * sg], y0 = pk0[4 * sg + 2];
                    asm volatile("v_permlane32_swap_b32 %0, %1" : "+v"(x0), "+v"(y0));
                    unsigned int x1 = pk0[4 * sg + 1], y1 = pk0[4 * sg + 3];
                    asm volatile("v_permlane32_swap_b32 %0, %1" : "+v"(x1), "+v"(y1));
                    bfr[sg] = make_uint4(x0, x1, y0, y1);
                    unsigned int x2 = pk1[4 * sg], y2 = pk1[4 * sg + 2];
                    asm volatile("v_permlane32_swap_b32 %0, %1" : "+v"(x2), "+v"(y2));
                    unsigned int x3 = pk1[4 * sg + 1], y3 = pk1[4 * sg + 3];
                    asm volatile("v_permlane32_swap_b32 %0, %1" : "+v"(x3), "+v"(y3));
                    bfr[2 + sg] = make_uint4(x2, x3, y2, y3);
                }
                __builtin_amdgcn_s_setprio(1);
#pragma unroll
                for (int ss = 0; ss < 4; ++ss) {
                    short8 pb = __builtin_bit_cast(short8, bfr[ss]);
                    int vc = (((2 * ss + hb) ^ xh) << 3);
#pragma unroll
                    for (int dt = 0; dt < 4; ++dt) {
                        short8 vf = *(const short8*)&Vs[cur][dt * 32 + ql][vc];
                        o[dt] = __builtin_amdgcn_mfma_f32_32x32x16_bf16(vf, pb, o[dt], 0, 0, 0);
                    }
                }
                __builtin_amdgcn_s_setprio(0);
            }
            if (tt + 1 < cnt) writeV(cur ^ 1);
            __syncthreads();
        }

        l_r += __shfl_xor(l_r, 32);
        if (direct) {
            float inv_l = 1.f / l_r;
            unsigned int* ep = (unsigned int*)smem + wave * 2176;
#pragma unroll
            for (int dt = 0; dt < 4; ++dt)
#pragma unroll
                for (int r = 0; r < 16; r += 2) {
                    float a = o[dt][r] * inv_l, c2 = o[dt][r + 1] * inv_l;
                    unsigned int pkv;
                    asm("v_cvt_pk_bf16_f32 %0, %1, %2" : "=v"(pkv) : "v"(a), "v"(c2));
                    ep[ql * 68 + dt * 16 + ((r & 3) >> 1) + 4 * (r >> 2) + 2 * hb] = pkv;
                }
#pragma unroll
            for (int it = 0; it < 8; ++it) {
                int qr = lane >> 1, ch = (lane & 1) * 8 + it;
                uint4 w = *(uint4*)&ep[qr * 68 + ch * 4];
                *(uint4*)(attn_out + (size_t)(kvB + q0w + qr) * 2048 + h * 128 + ch * 8) = w;
            }
        } else {
            float* sW = (float*)smem + wave * 4224;
#pragma unroll
            for (int dt = 0; dt < 4; ++dt)
#pragma unroll
                for (int r = 0; r < 16; ++r)
                    sW[ql * 132 + dt * 32 + (r & 3) + 8 * (r >> 2) + 4 * hb] = o[dt][r];
            const size_t pb2 = ((size_t)pairIdx * 2 + side);
            {
                int q = lane >> 1, half = lane & 1;
                const float* src = sW + q * 132 + half * 64;
                float* dst = partO + pb2 * 16384 + (wave * 32 + q) * 128 + half * 64;
#pragma unroll
                for (int j = 0; j < 64; j += 4) *(float4*)(dst + j) = *(const float4*)(src + j);
            }
            if (hb == 0) {
                partL[pb2 * 128 + wave * 32 + ql] = l_r;
                partM[pb2 * 128 + wave * 32 + ql] = m_raw;
            }
        }
    };

    if (roleA) {
        run(qb * 128, 0, 2 * qb + 2, true, 0);
        run(hiqb * 128, 0, xsp, false, 0);
    } else {
        run(hiqb * 128, xsp, 17, false, 1);
    }
}

// merge the two partials of each hi q-tile
__global__ __launch_bounds__(256) void merge_kernel(
    const float* __restrict__ partO, const float* __restrict__ partL,
    const float* __restrict__ partM, unsigned short* __restrict__ attn_out) {
    __shared__ float sA[128], sB[128], sI[128];
    const int p = blockIdx.x, tid = threadIdx.x;
    const int bh = p >> 3, qb = p & 7;
    const int b = bh >> 4, h = bh & 15;
    const int q0 = (15 - qb) * 128;
    const float sc2 = 0.12751744f;
    if (tid < 128) {
        float mA = partM[(size_t)(p * 2) * 128 + tid];
        float mB = partM[(size_t)(p * 2 + 1) * 128 + tid];
        float mM = fmaxf(mA, mB);
        float aA = exp2f((mA - mM) * sc2), aB = exp2f((mB - mM) * sc2);
        float lT = aA * partL[(size_t)(p * 2) * 128 + tid] + aB * partL[(size_t)(p * 2 + 1) * 128 + tid];
        sA[tid] = aA; sB[tid] = aB; sI[tid] = 1.f / lT;
    }
    __syncthreads();
    const int q = tid >> 1, half = tid & 1;
    const float aA = sA[q], aB = sB[q], inv = sI[q];
    const float* oA = partO + (size_t)(p * 2) * 16384 + q * 128 + half * 64;
    const float* oB = partO + (size_t)(p * 2 + 1) * 16384 + q * 128 + half * 64;
    unsigned short* dst = attn_out + (size_t)(b * SS + q0 + q) * 2048 + h * 128 + half * 64;
#pragma unroll
    for (int j = 0; j < 64; j += 4) {
        float4 a4 = *(const float4*)(oA + j);
        float4 b4 = *(const float4*)(oB + j);
        ushort4 u;
        u.x = f2bf((aA * a4.x + aB * b4.x) * inv);
        u.y = f2bf((aA * a4.y + aB * b4.y) * inv);
        u.z = f2bf((aA * a4.z + aB * b4.z) * inv);
        u.w = f2bf((aA * a4.w + aB * b4.w) * inv);
        *(ushort4*)(dst + j) = u;
    }
}

// ---------------- launcher ----------------

extern "C" void kernel_launch(void* const* d_in, const int* in_sizes, int n_in,
                              void* d_out, int out_size, void* d_ws, size_t ws_size,
                              hipStream_t stream) {
    const float* x     = (const float*)d_in[0];
    const float* W_dkv = (const float*)d_in[1];
    const float* W_dq  = (const float*)d_in[2];
    const float* W_kr  = (const float*)d_in[3];
    const float* W_qc  = (const float*)d_in[4];
    const float* W_qr  = (const float*)d_in[5];
    const float* W_uk  = (const float*)d_in[6];
    const float* W_uv  = (const float*)d_in[7];
    const float* W_o   = (const float*)d_in[8];
    float* out = (float*)d_out;

    size_t off = 0;
    auto alloc = [&](size_t bytes) {
        void* p = (char*)d_ws + off;
        off = (off + bytes + 255) & ~(size_t)255;
        return p;
    };
    unsigned short* WcatT = (unsigned short*)alloc((size_t)320 * 2048 * 2);
    unsigned short* Wq2T  = (unsigned short*)alloc((size_t)3072 * 128 * 2);
    unsigned short* WqcB  = (unsigned short*)alloc((size_t)16 * 128 * 64 * 2);
    unsigned short* WukB  = (unsigned short*)alloc((size_t)16 * 128 * 64 * 2);
    unsigned short* WuvB  = (unsigned short*)alloc((size_t)16 * 128 * 128 * 2);
    unsigned short* WoT   = (unsigned short*)alloc((size_t)2048 * 2048 * 2);
    unsigned short* WeffT = (unsigned short*)alloc((size_t)2048 * 2048 * 2);
    unsigned short* g1    = (unsigned short*)alloc((size_t)NTOK * 320 * 2);
    unsigned short* q_all = (unsigned short*)alloc((size_t)NTOK * QSTR * 2);
    unsigned short* ckv_t = (unsigned short*)alloc((size_t)2 * 128 * 2048 * 2);
    unsigned short* attn  = (unsigned short*)alloc((size_t)NTOK * 2048 * 2);
    float2* rope_tab      = (float2*)alloc((size_t)SS * 32 * sizeof(float2));
    float* partO          = (float*)alloc((size_t)256 * 2 * 16384 * 4);
    float* partL          = (float*)alloc((size_t)256 * 2 * 128 * 4);
    float* partM          = (float*)alloc((size_t)256 * 2 * 128 * 4);

    // 1: layouts + bf16 copies + rope table
    prep_kernel<<<6400, 256, 0, stream>>>(W_dkv, W_dq, W_kr, W_qc, W_qr, W_uk, W_uv, W_o,
                                          WcatT, Wq2T, WqcB, WukB, WuvB, WoT, rope_tab);
    // 2: absorbed-weight precomputes
    wqk_kernel<<<16, 256, 0, stream>>>(WqcB, WukB, Wq2T);
    weff_kernel<<<dim3(16, 16), 256, 0, stream>>>(WoT, WuvB, WeffT);
    // 3: latent GEMM (f32 A, conversion folded)
    gemm_lat_kernel<<<dim3(5, 32), 256, 0, stream>>>(x, WcatT, g1);
    // 4: c_kv transpose
    ckvt_kernel<<<dim3(32, 2, 2), 256, 0, stream>>>(g1, ckv_t);
    // 5: absorbed q projection (q_tilde | q_rope), K=128
    gemm_bf16_kernel<128, unsigned short, false><<<dim3(24, 32), 256, 0, stream>>>(
        g1 + 128, 320, Wq2T, 128, q_all, QSTR, NTOK, QSTR, 128);
    // 6: both ropes
    rope_all_kernel<<<512 + 8192, 256, 0, stream>>>(g1, q_all, rope_tab);
    // 7: attention (absorbed, split-pair balanced) + merge
    mla_attn_kernel<<<512, 256, 0, stream>>>(q_all, g1, ckv_t, attn, partO, partL, partM);
    merge_kernel<<<256, 256, 0, stream>>>(partO, partL, partM, attn);
    // 8: output projection with W_eff -> fp32 (XCD-swizzled)
    gemm_bf16_kernel<128, float, true><<<dim3(16, 32), 256, 0, stream>>>(
        attn, 2048, WeffT, 2048, out, 2048, NTOK, 2048, 2048);
}

// Round 10
// 228.261 us; speedup vs baseline: 1.0555x; 1.0555x over previous
//
#include <hip/hip_runtime.h>
#include <hip/hip_bf16.h>

typedef __attribute__((ext_vector_type(8))) short short8;
typedef __attribute__((ext_vector_type(4))) float f32x4;
typedef __attribute__((ext_vector_type(16))) float f32x16;

#define N_EMBED 2048
#define N_HEAD 16
#define BB 2
#define SS 2048
#define NTOK (BB*SS)          // 4096
#define HD2 192               // absorbed head dim: 128 latent + 64 rope
#define QSTR 3072             // q_all row stride = 16*192

__device__ __forceinline__ unsigned short f2bf(float f) {
    unsigned int b = __builtin_bit_cast(unsigned int, f);
    b += 0x7fffu + ((b >> 16) & 1u);
    return (unsigned short)(b >> 16);
}
__device__ __forceinline__ float bf2f(unsigned short u) {
    unsigned int b = ((unsigned int)u) << 16;
    return __builtin_bit_cast(float, b);
}

#define GLOAD_LDS16(gsrc, ldst) __builtin_amdgcn_global_load_lds( \
    (const __attribute__((address_space(1))) void*)(gsrc), \
    (__attribute__((address_space(3))) void*)(ldst), 16, 0, 0)

#define ROPE_COEF (-0.28782313662425575f)  // -ln(10000)/32

// ---------------- prep: layouts + bf16 copies + rope table ----------------
__global__ __launch_bounds__(256) void prep_kernel(
    const float* __restrict__ Wdkv, const float* __restrict__ Wdq, const float* __restrict__ Wkr,
    const float* __restrict__ Wqc, const float* __restrict__ Wqr,
    const float* __restrict__ Wuk, const float* __restrict__ Wuv, const float* __restrict__ Wo,
    unsigned short* __restrict__ WcatT, unsigned short* __restrict__ Wq2T,
    unsigned short* __restrict__ WqcB, unsigned short* __restrict__ WukB,
    unsigned short* __restrict__ WuvB, unsigned short* __restrict__ WoT,
    float2* __restrict__ rope_tab) {
    __shared__ float tile[64][65];
    const int bid = blockIdx.x, tid = threadIdx.x;
    if (bid < 2560) {                       // WcatT [320][2048]
        int i = bid * 256 + tid;
        int n = i >> 11, k = i & 2047;
        float v;
        if (n < 128)      v = Wdkv[k * 128 + n];
        else if (n < 256) v = Wdq[k * 128 + (n - 128)];
        else              v = Wkr[k * 64 + (n - 256)];
        WcatT[i] = f2bf(v);
    } else if (bid < 3072) {                // Wq2T rope rows: [h][64 jr][128 k]
        int i = (bid - 2560) * 256 + tid;
        int h = i >> 13, jr = (i >> 7) & 63, k = i & 127;
        Wq2T[((size_t)(h * HD2 + 128 + jr)) * 128 + k] = f2bf(Wqr[(h * 128 + k) * 64 + jr]);
    } else if (bid < 3584) {                // WqcB plain copy [16][128][64]
        int i = (bid - 3072) * 256 + tid;
        WqcB[i] = f2bf(Wqc[i]);
    } else if (bid < 4096) {                // WukB plain copy
        int i = (bid - 3584) * 256 + tid;
        WukB[i] = f2bf(Wuk[i]);
    } else if (bid < 5120) {                // WuvB plain copy [16][128][128]
        int i = (bid - 4096) * 256 + tid;
        WuvB[i] = f2bf(Wuv[i]);
    } else if (bid < 6144) {                // WoT [2048][2048] tiled transpose
        int tb = bid - 5120;
        const int k0 = (tb & 31) * 64, n0 = (tb >> 5) * 64;
        const int tr = tid >> 4, tc = (tid & 15) * 4;
#pragma unroll
        for (int it = 0; it < 4; ++it) {
            int r = it * 16 + tr;
            float4 v = *(const float4*)(Wo + (size_t)(k0 + r) * 2048 + n0 + tc);
            tile[r][tc] = v.x; tile[r][tc + 1] = v.y; tile[r][tc + 2] = v.z; tile[r][tc + 3] = v.w;
        }
        __syncthreads();
#pragma unroll
        for (int it = 0; it < 4; ++it) {
            int r = it * 16 + tr;
            ushort4 o;
            o.x = f2bf(tile[tc][r]); o.y = f2bf(tile[tc + 1][r]);
            o.z = f2bf(tile[tc + 2][r]); o.w = f2bf(tile[tc + 3][r]);
            *(ushort4*)(WoT + (size_t)(n0 + r) * 2048 + k0 + tc) = o;
        }
    } else {                                // rope table [SS][32]
        int i = (bid - 6144) * 256 + tid;
        int pos = i >> 5, j = i & 31;
        float freq = __expf(ROPE_COEF * (float)j);
        float a = (float)pos * freq;
        float s, c;
        __sincosf(a, &s, &c);
        rope_tab[i] = make_float2(c, s);
    }
}

// ---------------- W_qk[h] = W_qc[h] @ W_uk[h]^T -> Wq2T rows h*192+[0,128) ----------------
__global__ __launch_bounds__(256) void wqk_kernel(
    const unsigned short* __restrict__ WqcB,   // [16][128][64]
    const unsigned short* __restrict__ WukB,   // [16][128][64]
    unsigned short* __restrict__ Wq2T) {       // [3072][128]
    const int h = blockIdx.x;
    const int tid = threadIdx.x, wave = tid >> 6, lane = tid & 63;
    const int wr = wave >> 1, wc = wave & 1;
    const int lg = lane >> 4, lr = lane & 15;
    const unsigned short* A = WqcB + (size_t)h * 8192;
    const unsigned short* Bt = WukB + (size_t)h * 8192;
    f32x4 acc[4][4] = {};
#pragma unroll
    for (int kk = 0; kk < 2; ++kk) {
        short8 af[4], bfr[4];
#pragma unroll
        for (int i = 0; i < 4; i++) af[i] = *(const short8*)(A + (wr * 64 + i * 16 + lr) * 64 + kk * 32 + lg * 8);
#pragma unroll
        for (int j = 0; j < 4; j++) bfr[j] = *(const short8*)(Bt + (wc * 64 + j * 16 + lr) * 64 + kk * 32 + lg * 8);
#pragma unroll
        for (int i = 0; i < 4; i++)
#pragma unroll
            for (int j = 0; j < 4; j++)
                acc[i][j] = __builtin_amdgcn_mfma_f32_16x16x32_bf16(af[i], bfr[j], acc[i][j], 0, 0, 0);
    }
#pragma unroll
    for (int i = 0; i < 4; i++)
#pragma unroll
        for (int j = 0; j < 4; j++)
#pragma unroll
            for (int r = 0; r < 4; r++) {
                int row = wr * 64 + i * 16 + lg * 4 + r;   // k_in
                int col = wc * 64 + j * 16 + lr;           // latent k'
                Wq2T[((size_t)(h * HD2 + col)) * 128 + row] = f2bf(acc[i][j][r]);
            }
}

// ---------------- W_effT[e][h*128+dl] = sum_dh WuvB[h][dl][dh] * WoT[e][h*128+dh] ----------------
__global__ __launch_bounds__(256) void weff_kernel(
    const unsigned short* __restrict__ WoT,    // [2048][2048]
    const unsigned short* __restrict__ WuvB,   // [16][128][128]
    unsigned short* __restrict__ WeffT) {      // [2048][2048]
    constexpr int BK = 32;
    __shared__ __align__(16) unsigned short As[2][128][BK];
    __shared__ __align__(16) unsigned short Bs[2][128][BK];
    const int et = blockIdx.x, h = blockIdx.y;
    const int tid = threadIdx.x, wave = tid >> 6, lane = tid & 63;
    const int wr = wave >> 1, wc = wave & 1;
    const int lg = lane >> 4, lr = lane & 15;
    const unsigned short* A = WoT + (size_t)et * 128 * 2048 + h * 128;  // rows e, lda 2048
    const unsigned short* Bt = WuvB + (size_t)h * 16384;                // [128][128]

    f32x4 acc[4][4] = {};
    auto stage = [&](int k0, int buf) {
#pragma unroll
        for (int it = 0; it < 2; ++it) {
            int e = (tid + it * 256) * 8;
            GLOAD_LDS16(A + (size_t)(e >> 5) * 2048 + k0 + (e & 31), &As[buf][0][0] + e);
        }
#pragma unroll
        for (int it = 0; it < 2; ++it) {
            int e = (tid + it * 256) * 8;
            GLOAD_LDS16(Bt + (size_t)(e >> 5) * 128 + k0 + (e & 31), &Bs[buf][0][0] + e);
        }
    };
    stage(0, 0);
    __syncthreads();
    for (int t = 0; t < 4; ++t) {
        const int cur = t & 1;
        if (t + 1 < 4) stage((t + 1) * BK, cur ^ 1);
        short8 af[4], bfr[4];
#pragma unroll
        for (int i = 0; i < 4; i++) af[i] = *(const short8*)&As[cur][wr * 64 + i * 16 + lr][lg * 8];
#pragma unroll
        for (int j = 0; j < 4; j++) bfr[j] = *(const short8*)&Bs[cur][wc * 64 + j * 16 + lr][lg * 8];
#pragma unroll
        for (int i = 0; i < 4; i++)
#pragma unroll
            for (int j = 0; j < 4; j++)
                acc[i][j] = __builtin_amdgcn_mfma_f32_16x16x32_bf16(af[i], bfr[j], acc[i][j], 0, 0, 0);
        __syncthreads();
    }
#pragma unroll
    for (int i = 0; i < 4; i++)
#pragma unroll
        for (int j = 0; j < 4; j++)
#pragma unroll
            for (int r = 0; r < 4; r++) {
                int row = et * 128 + wr * 64 + i * 16 + lg * 4 + r;   // e
                int col = wc * 64 + j * 16 + lr;                      // dl
                WeffT[(size_t)row * 2048 + h * 128 + col] = f2bf(acc[i][j][r]);
            }
}

// ---------------- ckv_t[b][dl][s] = g1[b*SS+s][dl] ----------------
__global__ __launch_bounds__(256) void ckvt_kernel(
    const unsigned short* __restrict__ g1, unsigned short* __restrict__ ckv_t) {
    __shared__ unsigned short tile[64][65];
    const int s0 = blockIdx.x * 64, d0 = blockIdx.y * 64, b = blockIdx.z;
    const int tid = threadIdx.x;
    const int tr = tid >> 4, tc = (tid & 15) * 4;
#pragma unroll
    for (int it = 0; it < 4; ++it) {
        int r = it * 16 + tr;
        *(ushort4*)&tile[r][tc] = *(const ushort4*)(g1 + (size_t)(b * SS + s0 + r) * 320 + d0 + tc);
    }
    __syncthreads();
#pragma unroll
    for (int it = 0; it < 4; ++it) {
        int r = it * 16 + tr;
        ushort4 o;
        o.x = tile[tc][r]; o.y = tile[tc + 1][r]; o.z = tile[tc + 2][r]; o.w = tile[tc + 3][r];
        *(ushort4*)(ckv_t + ((size_t)b * 128 + d0 + r) * 2048 + s0 + tc) = o;
    }
}

// ---------------- fused rope ----------------
__global__ __launch_bounds__(256) void rope_all_kernel(
    unsigned short* __restrict__ g1, unsigned short* __restrict__ q,
    const float2* __restrict__ tab) {
    const int bid = blockIdx.x, tid = threadIdx.x;
    if (bid < 512) {                        // k_rope: NTOK*32
        int i = bid * 256 + tid;
        int j = i & 31, row = i >> 5;
        int pos = row & (SS - 1);
        float2 cs = tab[(pos << 5) | j];
        unsigned short* p = g1 + (size_t)row * 320 + 256 + 2 * j;
        float x0 = bf2f(p[0]), x1 = bf2f(p[1]);
        p[0] = f2bf(x0 * cs.x - x1 * cs.y);
        p[1] = f2bf(x0 * cs.y + x1 * cs.x);
    } else {                                // q_rope: NTOK*16*32
        int i = (bid - 512) * 256 + tid;
        int j = i & 31, h = (i >> 5) & 15, row = i >> 9;
        int pos = row & (SS - 1);
        float2 cs = tab[(pos << 5) | j];
        unsigned short* p = q + (size_t)row * QSTR + h * HD2 + 128 + 2 * j;
        float x0 = bf2f(p[0]), x1 = bf2f(p[1]);
        p[0] = f2bf(x0 * cs.x - x1 * cs.y);
        p[1] = f2bf(x0 * cs.y + x1 * cs.x);
    }
}

// ---------------- GEMM (2-phase dbuf): C[M,N] = A[M,K] * Bt[N,K]^T ----------------

__device__ __forceinline__ void store_c(float* p, float v) { *p = v; }
__device__ __forceinline__ void store_c(unsigned short* p, float v) { *p = f2bf(v); }

template <int BN, typename CT, bool SWZ>
__global__ __launch_bounds__(256) void gemm_bf16_kernel(
    const unsigned short* __restrict__ A, int lda,
    const unsigned short* __restrict__ Bt, int ldb,
    CT* __restrict__ C, int ldc,
    int M, int N, int K) {
    constexpr int BM = 128, BK = 32;
    __shared__ __align__(16) unsigned short As[2][BM][BK];
    __shared__ __align__(16) unsigned short Bs[2][BN][BK];
    constexpr int WN = BN / 2;
    constexpr int FM = 4, FN = WN / 16;
    const int tid = threadIdx.x, wave = tid >> 6, lane = tid & 63;
    const int wr = wave >> 1, wc = wave & 1;
    const int lg = lane >> 4, lr = lane & 15;
    int m0, n0;
    if (SWZ) {
        int id = blockIdx.y * gridDim.x + blockIdx.x;
        int tot = gridDim.x * gridDim.y;
        int swz = (id & 7) * (tot >> 3) + (id >> 3);
        n0 = (swz % gridDim.x) * BN;
        m0 = (swz / gridDim.x) * BM;
    } else {
        m0 = blockIdx.y * BM; n0 = blockIdx.x * BN;
    }

    f32x4 acc[FM][FN] = {};

    auto stage = [&](int k0, int buf) {
#pragma unroll
        for (int it = 0; it < (BM * BK) / 2048; ++it) {
            int e = (tid + it * 256) * 8;
            GLOAD_LDS16(A + (size_t)(m0 + (e >> 5)) * lda + k0 + (e & 31), &As[buf][0][0] + e);
        }
#pragma unroll
        for (int it = 0; it < (BN * BK) / 2048; ++it) {
            int e = (tid + it * 256) * 8;
            GLOAD_LDS16(Bt + (size_t)(n0 + (e >> 5)) * ldb + k0 + (e & 31), &Bs[buf][0][0] + e);
        }
    };

    const int nk = K / BK;
    stage(0, 0);
    __syncthreads();
    for (int t = 0; t < nk; ++t) {
        const int cur = t & 1;
        if (t + 1 < nk) stage((t + 1) * BK, cur ^ 1);
        short8 af[FM], bfr[FN];
#pragma unroll
        for (int i = 0; i < FM; i++) af[i] = *(const short8*)&As[cur][wr * 64 + i * 16 + lr][lg * 8];
#pragma unroll
        for (int j = 0; j < FN; j++) bfr[j] = *(const short8*)&Bs[cur][wc * WN + j * 16 + lr][lg * 8];
#pragma unroll
        for (int i = 0; i < FM; i++)
#pragma unroll
            for (int j = 0; j < FN; j++)
                acc[i][j] = __builtin_amdgcn_mfma_f32_16x16x32_bf16(af[i], bfr[j], acc[i][j], 0, 0, 0);
        __syncthreads();
    }
#pragma unroll
    for (int i = 0; i < FM; i++)
#pragma unroll
        for (int j = 0; j < FN; j++)
#pragma unroll
            for (int r = 0; r < 4; r++) {
                int row = m0 + wr * 64 + i * 16 + lg * 4 + r;
                int col = n0 + wc * WN + j * 16 + lr;
                store_c(&C[(size_t)row * ldc + col], acc[i][j][r]);
            }
}

// Latent GEMM with f32 A (conversion folded in)
__global__ __launch_bounds__(256) void gemm_lat_kernel(
    const float* __restrict__ A,               // [NTOK][2048] f32
    const unsigned short* __restrict__ Bt,     // WcatT [320][2048]
    unsigned short* __restrict__ C) {          // g1 [NTOK][320]
    constexpr int BM = 128, BN = 64, BK = 32, K = 2048;
    __shared__ __align__(16) unsigned short As[2][BM][BK];
    __shared__ __align__(16) unsigned short Bs[2][BN][BK];
    constexpr int WN = BN / 2, FM = 4, FN = WN / 16;
    const int tid = threadIdx.x, wave = tid >> 6, lane = tid & 63;
    const int wr = wave >> 1, wc = wave & 1;
    const int lg = lane >> 4, lr = lane & 15;
    const int m0 = blockIdx.y * BM, n0 = blockIdx.x * BN;

    f32x4 acc[FM][FN] = {};
    const int ar = (tid * 16) >> 5, ac = (tid * 16) & 31;

    float4 a4[4];
    auto loadA = [&](int k0) {
        const float* src = A + (size_t)(m0 + ar) * K + k0 + ac;
#pragma unroll
        for (int i = 0; i < 4; ++i) a4[i] = *(const float4*)(src + i * 4);
    };
    auto writeA = [&](int buf) {
        unsigned int pk[8];
        const float* f = (const float*)a4;
#pragma unroll
        for (int i = 0; i < 8; ++i)
            asm("v_cvt_pk_bf16_f32 %0, %1, %2" : "=v"(pk[i]) : "v"(f[2 * i]), "v"(f[2 * i + 1]));
        *(uint4*)&As[buf][ar][ac]     = make_uint4(pk[0], pk[1], pk[2], pk[3]);
        *(uint4*)&As[buf][ar][ac + 8] = make_uint4(pk[4], pk[5], pk[6], pk[7]);
    };
    auto stageB = [&](int k0, int buf) {
        int e = tid * 8;
        GLOAD_LDS16(Bt + (size_t)(n0 + (e >> 5)) * K + k0 + (e & 31), &Bs[buf][0][0] + e);
    };

    loadA(0); stageB(0, 0); writeA(0);
    __syncthreads();
    constexpr int nk = K / BK;
    for (int t = 0; t < nk; ++t) {
        const int cur = t & 1;
        if (t + 1 < nk) { loadA((t + 1) * BK); stageB((t + 1) * BK, cur ^ 1); }
        short8 af[FM], bfr[FN];
#pragma unroll
        for (int i = 0; i < FM; i++) af[i] = *(const short8*)&As[cur][wr * 64 + i * 16 + lr][lg * 8];
#pragma unroll
        for (int j = 0; j < FN; j++) bfr[j] = *(const short8*)&Bs[cur][wc * WN + j * 16 + lr][lg * 8];
#pragma unroll
        for (int i = 0; i < FM; i++)
#pragma unroll
            for (int j = 0; j < FN; j++)
                acc[i][j] = __builtin_amdgcn_mfma_f32_16x16x32_bf16(af[i], bfr[j], acc[i][j], 0, 0, 0);
        if (t + 1 < nk) writeA(cur ^ 1);
        __syncthreads();
    }
#pragma unroll
    for (int i = 0; i < FM; i++)
#pragma unroll
        for (int j = 0; j < FN; j++)
#pragma unroll
            for (int r = 0; r < 4; r++) {
                int row = m0 + wr * 64 + i * 16 + lg * 4 + r;
                int col = n0 + wc * WN + j * 16 + lr;
                C[(size_t)row * 320 + col] = f2bf(acc[i][j][r]);
            }
}

// ---------------- flash attention v9: absorbed, 2 heads/block, split-pair balance ----------------
// 256 blocks x 512 threads (8 waves): waves 0-3 head h0, waves 4-7 head h0+1 —
// ONE K/V staging stream serves both heads (K/V head-independent after absorption).
// Split-pair schedule per block (roleA: lo full + hi[0,x); roleB: hi[x,..)) = 34
// tile-unit computes/block, exactly balanced. partO stored bf16.
__global__ __launch_bounds__(512) void mla_attn_kernel(
    const unsigned short* __restrict__ q_all,   // [NTOK][3072]: per head [qtil(128)|qrope(64)]
    const unsigned short* __restrict__ g1,      // [NTOK][320]: ckv 0..127, roped k_r 256..319
    const unsigned short* __restrict__ ckv_t,   // [2][128][2048]
    unsigned short* __restrict__ attn_out,      // [NTOK][2048] (o_lat)
    unsigned short* __restrict__ partOb,        // [256 pair][2 side][128 q][128 d] bf16
    float* __restrict__ partL,
    float* __restrict__ partM) {
    __shared__ __align__(16) char smem[81920];
    auto Ks = (unsigned short (*)[64][192])smem;             // [2][64][192], chunk-swizzled
    auto Vs = (unsigned short (*)[128][64])(smem + 49152);   // [2][128][64], chunk-swizzled

    const int id = blockIdx.x;
    const int xcd = id & 7, loc = id >> 3;
    const int hp = 2 * xcd + (loc >> 4);        // head-pair 0..15
    const int s2 = loc & 15;
    const bool roleA = s2 < 8;
    const int qb = roleA ? s2 : s2 - 8;
    const int hiqb = 15 - qb, xsp = 15 - 2 * qb;
    const int b = hp >> 3;
    const int tid = threadIdx.x, wave = tid >> 6, lane = tid & 63;
    const int wg = wave & 3, hsel = wave >> 2;
    const int h = (hp & 7) * 2 + hsel;
    const int bh = b * 16 + h;
    const int pairIdx = bh * 8 + qb;
    const int ql = lane & 31, hb = lane >> 5;
    const int kvB = b * SS;
    const float sc2 = 0.12751744f;   // (1/sqrt(128)) * log2(e)
    const int xh = ql & 7;

    uint4 vreg[2];
    auto stageK = [&](int t, int bufi) {
        // 64 rows x 24 chunks = 1536; slot s of row r holds global chunk c = s^(r&7)
#pragma unroll
        for (int it = 0; it < 3; ++it) {
            int cid = tid + it * 512;
            int r = cid / 24, s = cid - r * 24;
            int c = s ^ (r & 7);
            int col = (c < 16) ? c * 8 : 256 + (c - 16) * 8;
            GLOAD_LDS16(g1 + (size_t)(kvB + t * 64 + r) * 320 + col,
                        &Ks[bufi][0][0] + cid * 8);
        }
    };
    auto loadV = [&](int t) {
#pragma unroll
        for (int it = 0; it < 2; ++it) {
            int e = tid * 8 + it * 4096;
            vreg[it] = *(const uint4*)(ckv_t + ((size_t)b * 128 + (e >> 6)) * 2048 + t * 64 + (e & 63));
        }
    };
    auto writeV = [&](int bufi) {
#pragma unroll
        for (int it = 0; it < 2; ++it) {
            int e = tid * 8 + it * 4096;
            int d = e >> 6, j = (e & 63) >> 3;
            *(uint4*)&Vs[bufi][d][(j ^ (d & 7)) * 8] = vreg[it];
        }
    };

    auto run = [&](int q0, int t0, int cnt, bool direct, int side) {
        __syncthreads();   // fence prior smem use before restaging
        const int q0w = q0 + wg * 32;
        const int qg = q0w + ql;

        short8 qf[12];
        {
            const unsigned short* qp = q_all + (size_t)(kvB + qg) * QSTR + h * HD2 + hb * 8;
#pragma unroll
            for (int ss = 0; ss < 12; ++ss) qf[ss] = *(const short8*)(qp + 16 * ss);
        }
        f32x16 o[4] = {};
        float m_raw = -3e38f, mb = 0.f, l_r = 0.f;

        stageK(t0, 0);
        loadV(t0);
        writeV(0);
        __syncthreads();

        for (int tt = 0; tt < cnt; ++tt) {
            const int t = t0 + tt;
            const int cur = tt & 1;
            if (tt + 1 < cnt) { stageK(t + 1, cur ^ 1); loadV(t + 1); }
            {
                f32x16 p0 = {}, p1 = {};
                __builtin_amdgcn_s_setprio(1);
#pragma unroll
                for (int ss = 0; ss < 12; ++ss) {
                    int pc = (((2 * ss + hb) ^ xh) << 3);
                    short8 k0 = *(const short8*)&Ks[cur][ql][pc];
                    short8 k1 = *(const short8*)&Ks[cur][32 + ql][pc];
                    p0 = __builtin_amdgcn_mfma_f32_32x32x16_bf16(k0, qf[ss], p0, 0, 0, 0);
                    p1 = __builtin_amdgcn_mfma_f32_32x32x16_bf16(k1, qf[ss], p1, 0, 0, 0);
                }
                __builtin_amdgcn_s_setprio(0);
                const int kv0 = t * 64;
                if (kv0 + 63 > q0w) {
#pragma unroll
                    for (int r = 0; r < 16; ++r) {
                        int kvg = kv0 + (r & 3) + 8 * (r >> 2) + 4 * hb;
                        if (kvg > qg) p0[r] = -3e38f;
                        if (kvg + 32 > qg) p1[r] = -3e38f;
                    }
                }
                float pm = -3e38f;
#pragma unroll
                for (int r = 0; r < 16; ++r) pm = fmaxf(pm, fmaxf(p0[r], p1[r]));
                pm = fmaxf(pm, __shfl_xor(pm, 32));
                if (__any(pm > m_raw + 64.f)) {   // defer-max (T13)
                    float mn = fmaxf(m_raw, pm);
                    float alpha = exp2f((m_raw - mn) * sc2);
                    m_raw = mn; mb = mn * sc2;
                    l_r *= alpha;
#pragma unroll
                    for (int dt = 0; dt < 4; ++dt)
#pragma unroll
                        for (int r = 0; r < 16; ++r) o[dt][r] *= alpha;
                }
                float ps = 0.f;
#pragma unroll
                for (int r = 0; r < 16; ++r) {
                    p0[r] = exp2f(__builtin_fmaf(p0[r], sc2, -mb));
                    p1[r] = exp2f(__builtin_fmaf(p1[r], sc2, -mb));
                    ps += p0[r] + p1[r];
                }
                l_r += ps;
                unsigned int pk0[8], pk1[8];
#pragma unroll
                for (int i = 0; i < 8; ++i) {
                    asm("v_cvt_pk_bf16_f32 %0, %1, %2" : "=v"(pk0[i]) : "v"(p0[2 * i]), "v"(p0[2 * i + 1]));
                    asm("v_cvt_pk_bf16_f32 %0, %1, %2" : "=v"(pk1[i]) : "v"(p1[2 * i]), "v"(p1[2 * i + 1]));
                }
                uint4 bfr[4];
#pragma unroll
                for (int sg = 0; sg < 2; ++sg) {
                    unsigned int x0 = pk0[4 * sg], y0 = pk0[4 * sg + 2];
                    asm volatile("v_permlane32_swap_b32 %0, %1" : "+v"(x0), "+v"(y0));
                    unsigned int x1 = pk0[4 * sg + 1], y1 = pk0[4 * sg + 3];
                    asm volatile("v_permlane32_swap_b32 %0, %1" : "+v"(x1), "+v"(y1));
                    bfr[sg] = make_uint4(x0, x1, y0, y1);
                    unsigned int x2 = pk1[4 * sg], y2 = pk1[4 * sg + 2];
                    asm volatile("v_permlane32_swap_b32 %0, %1" : "+v"(x2), "+v"(y2));
                    unsigned int x3 = pk1[4 * sg + 1], y3 = pk1[4 * sg + 3];
                    asm volatile("v_permlane32_swap_b32 %0, %1" : "+v"(x3), "+v"(y3));
                    bfr[2 + sg] = make_uint4(x2, x3, y2, y3);
                }
                __builtin_amdgcn_s_setprio(1);
#pragma unroll
                for (int ss = 0; ss < 4; ++ss) {
                    short8 pb = __builtin_bit_cast(short8, bfr[ss]);
                    int vc = (((2 * ss + hb) ^ xh) << 3);
#pragma unroll
                    for (int dt = 0; dt < 4; ++dt) {
                        short8 vf = *(const short8*)&Vs[cur][dt * 32 + ql][vc];
                        o[dt] = __builtin_amdgcn_mfma_f32_32x32x16_bf16(vf, pb, o[dt], 0, 0, 0);
                    }
                }
                __builtin_amdgcn_s_setprio(0);
            }
            if (tt + 1 < cnt) writeV(cur ^ 1);
            __syncthreads();
        }

        l_r += __shfl_xor(l_r, 32);
        if (direct) {
            float inv_l = 1.f / l_r;
            unsigned int* ep = (unsigned int*)smem + wave * 2176;   // 8 x 8704B = 69632 <= 81920
#pragma unroll
            for (int dt = 0; dt < 4; ++dt)
#pragma unroll
                for (int r = 0; r < 16; r += 2) {
                    float a = o[dt][r] * inv_l, c2 = o[dt][r + 1] * inv_l;
                    unsigned int pkv;
                    asm("v_cvt_pk_bf16_f32 %0, %1, %2" : "=v"(pkv) : "v"(a), "v"(c2));
                    ep[ql * 68 + dt * 16 + ((r & 3) >> 1) + 4 * (r >> 2) + 2 * hb] = pkv;
                }
#pragma unroll
            for (int it = 0; it < 8; ++it) {
                int qr = lane >> 1, ch = (lane & 1) * 8 + it;
                uint4 w = *(uint4*)&ep[qr * 68 + ch * 4];
                *(uint4*)(attn_out + (size_t)(kvB + q0w + qr) * 2048 + h * 128 + ch * 8) = w;
            }
        } else {
            // partial: LDS transpose (two wave-passes to fit 67KB scratch), store bf16
            float* sW = (float*)smem + wg * 4224;   // 4 regions x 16896B
            const size_t pb2 = ((size_t)pairIdx * 2 + side);
#pragma unroll
            for (int pass = 0; pass < 2; ++pass) {
                if (pass == 1) __syncthreads();
                if (hsel == pass) {
#pragma unroll
                    for (int dt = 0; dt < 4; ++dt)
#pragma unroll
                        for (int r = 0; r < 16; ++r)
                            sW[ql * 132 + dt * 32 + (r & 3) + 8 * (r >> 2) + 4 * hb] = o[dt][r];
                    int q = lane >> 1, half = lane & 1;
                    const float* src = sW + q * 132 + half * 64;
                    unsigned int* dst = (unsigned int*)(partOb + pb2 * 16384 + ((size_t)(wg * 32 + q)) * 128 + half * 64);
#pragma unroll
                    for (int j = 0; j < 64; j += 4) {
                        float4 f = *(const float4*)(src + j);
                        unsigned int d0, d1;
                        asm("v_cvt_pk_bf16_f32 %0, %1, %2" : "=v"(d0) : "v"(f.x), "v"(f.y));
                        asm("v_cvt_pk_bf16_f32 %0, %1, %2" : "=v"(d1) : "v"(f.z), "v"(f.w));
                        *(uint2*)(dst + (j >> 1)) = make_uint2(d0, d1);
                    }
                    if (hb == 0) {
                        partL[pb2 * 128 + wg * 32 + ql] = l_r;
                        partM[pb2 * 128 + wg * 32 + ql] = m_raw;
                    }
                }
            }
        }
    };

    if (roleA) {
        run(qb * 128, 0, 2 * qb + 2, true, 0);
        run(hiqb * 128, 0, xsp, false, 0);
    } else {
        run(hiqb * 128, xsp, 17, false, 1);
    }
}

// merge the two partials of each hi q-tile (bf16 partO)
__global__ __launch_bounds__(256) void merge_kernel(
    const unsigned short* __restrict__ partOb, const float* __restrict__ partL,
    const float* __restrict__ partM, unsigned short* __restrict__ attn_out) {
    __shared__ float sA[128], sB[128], sI[128];
    const int p = blockIdx.x, tid = threadIdx.x;
    const int bh = p >> 3, qb = p & 7;
    const int b = bh >> 4, h = bh & 15;
    const int q0 = (15 - qb) * 128;
    const float sc2 = 0.12751744f;
    if (tid < 128) {
        float mA = partM[(size_t)(p * 2) * 128 + tid];
        float mB = partM[(size_t)(p * 2 + 1) * 128 + tid];
        float mM = fmaxf(mA, mB);
        float aA = exp2f((mA - mM) * sc2), aB = exp2f((mB - mM) * sc2);
        float lT = aA * partL[(size_t)(p * 2) * 128 + tid] + aB * partL[(size_t)(p * 2 + 1) * 128 + tid];
        sA[tid] = aA; sB[tid] = aB; sI[tid] = 1.f / lT;
    }
    __syncthreads();
    const int q = tid >> 1, half = tid & 1;
    const float aA = sA[q], aB = sB[q], inv = sI[q];
    const unsigned short* oA = partOb + (size_t)(p * 2) * 16384 + q * 128 + half * 64;
    const unsigned short* oB = partOb + (size_t)(p * 2 + 1) * 16384 + q * 128 + half * 64;
    unsigned short* dst = attn_out + (size_t)(b * SS + q0 + q) * 2048 + h * 128 + half * 64;
#pragma unroll
    for (int j = 0; j < 64; j += 4) {
        ushort4 ua = *(const ushort4*)(oA + j);
        ushort4 ub = *(const ushort4*)(oB + j);
        ushort4 u;
        u.x = f2bf((aA * bf2f(ua.x) + aB * bf2f(ub.x)) * inv);
        u.y = f2bf((aA * bf2f(ua.y) + aB * bf2f(ub.y)) * inv);
        u.z = f2bf((aA * bf2f(ua.z) + aB * bf2f(ub.z)) * inv);
        u.w = f2bf((aA * bf2f(ua.w) + aB * bf2f(ub.w)) * inv);
        *(ushort4*)(dst + j) = u;
    }
}

// ---------------- launcher ----------------

extern "C" void kernel_launch(void* const* d_in, const int* in_sizes, int n_in,
                              void* d_out, int out_size, void* d_ws, size_t ws_size,
                              hipStream_t stream) {
    const float* x     = (const float*)d_in[0];
    const float* W_dkv = (const float*)d_in[1];
    const float* W_dq  = (const float*)d_in[2];
    const float* W_kr  = (const float*)d_in[3];
    const float* W_qc  = (const float*)d_in[4];
    const float* W_qr  = (const float*)d_in[5];
    const float* W_uk  = (const float*)d_in[6];
    const float* W_uv  = (const float*)d_in[7];
    const float* W_o   = (const float*)d_in[8];
    float* out = (float*)d_out;

    size_t off = 0;
    auto alloc = [&](size_t bytes) {
        void* p = (char*)d_ws + off;
        off = (off + bytes + 255) & ~(size_t)255;
        return p;
    };
    unsigned short* WcatT = (unsigned short*)alloc((size_t)320 * 2048 * 2);
    unsigned short* Wq2T  = (unsigned short*)alloc((size_t)3072 * 128 * 2);
    unsigned short* WqcB  = (unsigned short*)alloc((size_t)16 * 128 * 64 * 2);
    unsigned short* WukB  = (unsigned short*)alloc((size_t)16 * 128 * 64 * 2);
    unsigned short* WuvB  = (unsigned short*)alloc((size_t)16 * 128 * 128 * 2);
    unsigned short* WoT   = (unsigned short*)alloc((size_t)2048 * 2048 * 2);
    unsigned short* WeffT = (unsigned short*)alloc((size_t)2048 * 2048 * 2);
    unsigned short* g1    = (unsigned short*)alloc((size_t)NTOK * 320 * 2);
    unsigned short* q_all = (unsigned short*)alloc((size_t)NTOK * QSTR * 2);
    unsigned short* ckv_t = (unsigned short*)alloc((size_t)2 * 128 * 2048 * 2);
    unsigned short* attn  = (unsigned short*)alloc((size_t)NTOK * 2048 * 2);
    float2* rope_tab      = (float2*)alloc((size_t)SS * 32 * sizeof(float2));
    unsigned short* partOb= (unsigned short*)alloc((size_t)256 * 2 * 16384 * 2);
    float* partL          = (float*)alloc((size_t)256 * 2 * 128 * 4);
    float* partM          = (float*)alloc((size_t)256 * 2 * 128 * 4);

    // 1: layouts + bf16 copies + rope table
    prep_kernel<<<6400, 256, 0, stream>>>(W_dkv, W_dq, W_kr, W_qc, W_qr, W_uk, W_uv, W_o,
                                          WcatT, Wq2T, WqcB, WukB, WuvB, WoT, rope_tab);
    // 2: absorbed-weight precomputes
    wqk_kernel<<<16, 256, 0, stream>>>(WqcB, WukB, Wq2T);
    weff_kernel<<<dim3(16, 16), 256, 0, stream>>>(WoT, WuvB, WeffT);
    // 3: latent GEMM (f32 A, conversion folded)
    gemm_lat_kernel<<<dim3(5, 32), 256, 0, stream>>>(x, WcatT, g1);
    // 4: c_kv transpose
    ckvt_kernel<<<dim3(32, 2, 2), 256, 0, stream>>>(g1, ckv_t);
    // 5: absorbed q projection (q_tilde | q_rope), K=128
    gemm_bf16_kernel<128, unsigned short, false><<<dim3(24, 32), 256, 0, stream>>>(
        g1 + 128, 320, Wq2T, 128, q_all, QSTR, NTOK, QSTR, 128);
    // 6: both ropes
    rope_all_kernel<<<512 + 8192, 256, 0, stream>>>(g1, q_all, rope_tab);
    // 7: attention (2 heads/block, split-pair balanced) + merge
    mla_attn_kernel<<<256, 512, 0, stream>>>(q_all, g1, ckv_t, attn, partOb, partL, partM);
    merge_kernel<<<256, 256, 0, stream>>>(partOb, partL, partM, attn);
    // 8: output projection with W_eff -> fp32 (XCD-swizzled)
    gemm_bf16_kernel<128, float, true><<<dim3(16, 32), 256, 0, stream>>>(
        attn, 2048, WeffT, 2048, out, 2048, NTOK, 2048, 2048);
}

// Round 11
// 224.591 us; speedup vs baseline: 1.0728x; 1.0163x over previous
//
#include <hip/hip_runtime.h>
#include <hip/hip_bf16.h>

typedef __attribute__((ext_vector_type(8))) short short8;
typedef __attribute__((ext_vector_type(4))) float f32x4;
typedef __attribute__((ext_vector_type(16))) float f32x16;

#define N_EMBED 2048
#define N_HEAD 16
#define BB 2
#define SS 2048
#define NTOK (BB*SS)          // 4096
#define HD2 192               // absorbed head dim: 128 latent + 64 rope
#define QSTR 3072             // q_all row stride = 16*192

__device__ __forceinline__ unsigned short f2bf(float f) {
    unsigned int b = __builtin_bit_cast(unsigned int, f);
    b += 0x7fffu + ((b >> 16) & 1u);
    return (unsigned short)(b >> 16);
}
__device__ __forceinline__ float bf2f(unsigned short u) {
    unsigned int b = ((unsigned int)u) << 16;
    return __builtin_bit_cast(float, b);
}

#define GLOAD_LDS16(gsrc, ldst) __builtin_amdgcn_global_load_lds( \
    (const __attribute__((address_space(1))) void*)(gsrc), \
    (__attribute__((address_space(3))) void*)(ldst), 16, 0, 0)

#define ROPE_COEF (-0.28782313662425575f)  // -ln(10000)/32

// ---------------- prep: layouts + bf16 copies + rope table ----------------
__global__ __launch_bounds__(256) void prep_kernel(
    const float* __restrict__ Wdkv, const float* __restrict__ Wdq, const float* __restrict__ Wkr,
    const float* __restrict__ Wqc, const float* __restrict__ Wqr,
    const float* __restrict__ Wuk, const float* __restrict__ Wuv, const float* __restrict__ Wo,
    unsigned short* __restrict__ WcatT, unsigned short* __restrict__ Wq2T,
    unsigned short* __restrict__ WqcB, unsigned short* __restrict__ WukB,
    unsigned short* __restrict__ WuvB, unsigned short* __restrict__ WoT,
    float2* __restrict__ rope_tab) {
    __shared__ float tile[64][65];
    const int bid = blockIdx.x, tid = threadIdx.x;
    if (bid < 2560) {                       // WcatT [320][2048]
        int i = bid * 256 + tid;
        int n = i >> 11, k = i & 2047;
        float v;
        if (n < 128)      v = Wdkv[k * 128 + n];
        else if (n < 256) v = Wdq[k * 128 + (n - 128)];
        else              v = Wkr[k * 64 + (n - 256)];
        WcatT[i] = f2bf(v);
    } else if (bid < 3072) {                // Wq2T rope rows: [h][64 jr][128 k]
        int i = (bid - 2560) * 256 + tid;
        int h = i >> 13, jr = (i >> 7) & 63, k = i & 127;
        Wq2T[((size_t)(h * HD2 + 128 + jr)) * 128 + k] = f2bf(Wqr[(h * 128 + k) * 64 + jr]);
    } else if (bid < 3584) {                // WqcB plain copy [16][128][64]
        int i = (bid - 3072) * 256 + tid;
        WqcB[i] = f2bf(Wqc[i]);
    } else if (bid < 4096) {                // WukB plain copy
        int i = (bid - 3584) * 256 + tid;
        WukB[i] = f2bf(Wuk[i]);
    } else if (bid < 5120) {                // WuvB plain copy [16][128][128]
        int i = (bid - 4096) * 256 + tid;
        WuvB[i] = f2bf(Wuv[i]);
    } else if (bid < 6144) {                // WoT [2048][2048] tiled transpose
        int tb = bid - 5120;
        const int k0 = (tb & 31) * 64, n0 = (tb >> 5) * 64;
        const int tr = tid >> 4, tc = (tid & 15) * 4;
#pragma unroll
        for (int it = 0; it < 4; ++it) {
            int r = it * 16 + tr;
            float4 v = *(const float4*)(Wo + (size_t)(k0 + r) * 2048 + n0 + tc);
            tile[r][tc] = v.x; tile[r][tc + 1] = v.y; tile[r][tc + 2] = v.z; tile[r][tc + 3] = v.w;
        }
        __syncthreads();
#pragma unroll
        for (int it = 0; it < 4; ++it) {
            int r = it * 16 + tr;
            ushort4 o;
            o.x = f2bf(tile[tc][r]); o.y = f2bf(tile[tc + 1][r]);
            o.z = f2bf(tile[tc + 2][r]); o.w = f2bf(tile[tc + 3][r]);
            *(ushort4*)(WoT + (size_t)(n0 + r) * 2048 + k0 + tc) = o;
        }
    } else {                                // rope table [SS][32]
        int i = (bid - 6144) * 256 + tid;
        int pos = i >> 5, j = i & 31;
        float freq = __expf(ROPE_COEF * (float)j);
        float a = (float)pos * freq;
        float s, c;
        __sincosf(a, &s, &c);
        rope_tab[i] = make_float2(c, s);
    }
}

// ---------------- W_qk[h] = W_qc[h] @ W_uk[h]^T -> Wq2T rows h*192+[0,128) ----------------
__global__ __launch_bounds__(256) void wqk_kernel(
    const unsigned short* __restrict__ WqcB,   // [16][128][64]
    const unsigned short* __restrict__ WukB,   // [16][128][64]
    unsigned short* __restrict__ Wq2T) {       // [3072][128]
    const int h = blockIdx.x;
    const int tid = threadIdx.x, wave = tid >> 6, lane = tid & 63;
    const int wr = wave >> 1, wc = wave & 1;
    const int lg = lane >> 4, lr = lane & 15;
    const unsigned short* A = WqcB + (size_t)h * 8192;
    const unsigned short* Bt = WukB + (size_t)h * 8192;
    f32x4 acc[4][4] = {};
#pragma unroll
    for (int kk = 0; kk < 2; ++kk) {
        short8 af[4], bfr[4];
#pragma unroll
        for (int i = 0; i < 4; i++) af[i] = *(const short8*)(A + (wr * 64 + i * 16 + lr) * 64 + kk * 32 + lg * 8);
#pragma unroll
        for (int j = 0; j < 4; j++) bfr[j] = *(const short8*)(Bt + (wc * 64 + j * 16 + lr) * 64 + kk * 32 + lg * 8);
#pragma unroll
        for (int i = 0; i < 4; i++)
#pragma unroll
            for (int j = 0; j < 4; j++)
                acc[i][j] = __builtin_amdgcn_mfma_f32_16x16x32_bf16(af[i], bfr[j], acc[i][j], 0, 0, 0);
    }
#pragma unroll
    for (int i = 0; i < 4; i++)
#pragma unroll
        for (int j = 0; j < 4; j++)
#pragma unroll
            for (int r = 0; r < 4; r++) {
                int row = wr * 64 + i * 16 + lg * 4 + r;   // k_in
                int col = wc * 64 + j * 16 + lr;           // latent k'
                Wq2T[((size_t)(h * HD2 + col)) * 128 + row] = f2bf(acc[i][j][r]);
            }
}

// ---------------- W_effT[e][h*128+dl] = sum_dh WuvB[h][dl][dh] * WoT[e][h*128+dh] ----------------
__global__ __launch_bounds__(256) void weff_kernel(
    const unsigned short* __restrict__ WoT,    // [2048][2048]
    const unsigned short* __restrict__ WuvB,   // [16][128][128]
    unsigned short* __restrict__ WeffT) {      // [2048][2048]
    constexpr int BK = 32;
    __shared__ __align__(16) unsigned short As[2][128][BK];
    __shared__ __align__(16) unsigned short Bs[2][128][BK];
    const int et = blockIdx.x, h = blockIdx.y;
    const int tid = threadIdx.x, wave = tid >> 6, lane = tid & 63;
    const int wr = wave >> 1, wc = wave & 1;
    const int lg = lane >> 4, lr = lane & 15;
    const unsigned short* A = WoT + (size_t)et * 128 * 2048 + h * 128;  // rows e, lda 2048
    const unsigned short* Bt = WuvB + (size_t)h * 16384;                // [128][128]

    f32x4 acc[4][4] = {};
    auto stage = [&](int k0, int buf) {
#pragma unroll
        for (int it = 0; it < 2; ++it) {
            int e = (tid + it * 256) * 8;
            GLOAD_LDS16(A + (size_t)(e >> 5) * 2048 + k0 + (e & 31), &As[buf][0][0] + e);
        }
#pragma unroll
        for (int it = 0; it < 2; ++it) {
            int e = (tid + it * 256) * 8;
            GLOAD_LDS16(Bt + (size_t)(e >> 5) * 128 + k0 + (e & 31), &Bs[buf][0][0] + e);
        }
    };
    stage(0, 0);
    __syncthreads();
    for (int t = 0; t < 4; ++t) {
        const int cur = t & 1;
        if (t + 1 < 4) stage((t + 1) * BK, cur ^ 1);
        short8 af[4], bfr[4];
#pragma unroll
        for (int i = 0; i < 4; i++) af[i] = *(const short8*)&As[cur][wr * 64 + i * 16 + lr][lg * 8];
#pragma unroll
        for (int j = 0; j < 4; j++) bfr[j] = *(const short8*)&Bs[cur][wc * 64 + j * 16 + lr][lg * 8];
#pragma unroll
        for (int i = 0; i < 4; i++)
#pragma unroll
            for (int j = 0; j < 4; j++)
                acc[i][j] = __builtin_amdgcn_mfma_f32_16x16x32_bf16(af[i], bfr[j], acc[i][j], 0, 0, 0);
        __syncthreads();
    }
#pragma unroll
    for (int i = 0; i < 4; i++)
#pragma unroll
        for (int j = 0; j < 4; j++)
#pragma unroll
            for (int r = 0; r < 4; r++) {
                int row = et * 128 + wr * 64 + i * 16 + lg * 4 + r;   // e
                int col = wc * 64 + j * 16 + lr;                      // dl
                WeffT[(size_t)row * 2048 + h * 128 + col] = f2bf(acc[i][j][r]);
            }
}

// ---------------- ckv_t[b][dl][s] = g1[b*SS+s][dl] ----------------
__global__ __launch_bounds__(256) void ckvt_kernel(
    const unsigned short* __restrict__ g1, unsigned short* __restrict__ ckv_t) {
    __shared__ unsigned short tile[64][65];
    const int s0 = blockIdx.x * 64, d0 = blockIdx.y * 64, b = blockIdx.z;
    const int tid = threadIdx.x;
    const int tr = tid >> 4, tc = (tid & 15) * 4;
#pragma unroll
    for (int it = 0; it < 4; ++it) {
        int r = it * 16 + tr;
        *(ushort4*)&tile[r][tc] = *(const ushort4*)(g1 + (size_t)(b * SS + s0 + r) * 320 + d0 + tc);
    }
    __syncthreads();
#pragma unroll
    for (int it = 0; it < 4; ++it) {
        int r = it * 16 + tr;
        ushort4 o;
        o.x = tile[tc][r]; o.y = tile[tc + 1][r]; o.z = tile[tc + 2][r]; o.w = tile[tc + 3][r];
        *(ushort4*)(ckv_t + ((size_t)b * 128 + d0 + r) * 2048 + s0 + tc) = o;
    }
}

// ---------------- fused rope ----------------
__global__ __launch_bounds__(256) void rope_all_kernel(
    unsigned short* __restrict__ g1, unsigned short* __restrict__ q,
    const float2* __restrict__ tab) {
    const int bid = blockIdx.x, tid = threadIdx.x;
    if (bid < 512) {                        // k_rope: NTOK*32
        int i = bid * 256 + tid;
        int j = i & 31, row = i >> 5;
        int pos = row & (SS - 1);
        float2 cs = tab[(pos << 5) | j];
        unsigned short* p = g1 + (size_t)row * 320 + 256 + 2 * j;
        float x0 = bf2f(p[0]), x1 = bf2f(p[1]);
        p[0] = f2bf(x0 * cs.x - x1 * cs.y);
        p[1] = f2bf(x0 * cs.y + x1 * cs.x);
    } else {                                // q_rope: NTOK*16*32
        int i = (bid - 512) * 256 + tid;
        int j = i & 31, h = (i >> 5) & 15, row = i >> 9;
        int pos = row & (SS - 1);
        float2 cs = tab[(pos << 5) | j];
        unsigned short* p = q + (size_t)row * QSTR + h * HD2 + 128 + 2 * j;
        float x0 = bf2f(p[0]), x1 = bf2f(p[1]);
        p[0] = f2bf(x0 * cs.x - x1 * cs.y);
        p[1] = f2bf(x0 * cs.y + x1 * cs.x);
    }
}

// ---------------- GEMM (2-phase dbuf): C[M,N] = A[M,K] * Bt[N,K]^T ----------------

__device__ __forceinline__ void store_c(float* p, float v) { *p = v; }
__device__ __forceinline__ void store_c(unsigned short* p, float v) { *p = f2bf(v); }

template <int BN, typename CT, bool SWZ>
__global__ __launch_bounds__(256) void gemm_bf16_kernel(
    const unsigned short* __restrict__ A, int lda,
    const unsigned short* __restrict__ Bt, int ldb,
    CT* __restrict__ C, int ldc,
    int M, int N, int K) {
    constexpr int BM = 128, BK = 32;
    __shared__ __align__(16) unsigned short As[2][BM][BK];
    __shared__ __align__(16) unsigned short Bs[2][BN][BK];
    constexpr int WN = BN / 2;
    constexpr int FM = 4, FN = WN / 16;
    const int tid = threadIdx.x, wave = tid >> 6, lane = tid & 63;
    const int wr = wave >> 1, wc = wave & 1;
    const int lg = lane >> 4, lr = lane & 15;
    int m0, n0;
    if (SWZ) {
        int id = blockIdx.y * gridDim.x + blockIdx.x;
        int tot = gridDim.x * gridDim.y;
        int swz = (id & 7) * (tot >> 3) + (id >> 3);
        n0 = (swz % gridDim.x) * BN;
        m0 = (swz / gridDim.x) * BM;
    } else {
        m0 = blockIdx.y * BM; n0 = blockIdx.x * BN;
    }

    f32x4 acc[FM][FN] = {};

    auto stage = [&](int k0, int buf) {
#pragma unroll
        for (int it = 0; it < (BM * BK) / 2048; ++it) {
            int e = (tid + it * 256) * 8;
            GLOAD_LDS16(A + (size_t)(m0 + (e >> 5)) * lda + k0 + (e & 31), &As[buf][0][0] + e);
        }
#pragma unroll
        for (int it = 0; it < (BN * BK) / 2048; ++it) {
            int e = (tid + it * 256) * 8;
            GLOAD_LDS16(Bt + (size_t)(n0 + (e >> 5)) * ldb + k0 + (e & 31), &Bs[buf][0][0] + e);
        }
    };

    const int nk = K / BK;
    stage(0, 0);
    __syncthreads();
    for (int t = 0; t < nk; ++t) {
        const int cur = t & 1;
        if (t + 1 < nk) stage((t + 1) * BK, cur ^ 1);
        short8 af[FM], bfr[FN];
#pragma unroll
        for (int i = 0; i < FM; i++) af[i] = *(const short8*)&As[cur][wr * 64 + i * 16 + lr][lg * 8];
#pragma unroll
        for (int j = 0; j < FN; j++) bfr[j] = *(const short8*)&Bs[cur][wc * WN + j * 16 + lr][lg * 8];
#pragma unroll
        for (int i = 0; i < FM; i++)
#pragma unroll
            for (int j = 0; j < FN; j++)
                acc[i][j] = __builtin_amdgcn_mfma_f32_16x16x32_bf16(af[i], bfr[j], acc[i][j], 0, 0, 0);
        __syncthreads();
    }
#pragma unroll
    for (int i = 0; i < FM; i++)
#pragma unroll
        for (int j = 0; j < FN; j++)
#pragma unroll
            for (int r = 0; r < 4; r++) {
                int row = m0 + wr * 64 + i * 16 + lg * 4 + r;
                int col = n0 + wc * WN + j * 16 + lr;
                store_c(&C[(size_t)row * ldc + col], acc[i][j][r]);
            }
}

// Latent GEMM with f32 A (conversion folded in)
__global__ __launch_bounds__(256) void gemm_lat_kernel(
    const float* __restrict__ A,               // [NTOK][2048] f32
    const unsigned short* __restrict__ Bt,     // WcatT [320][2048]
    unsigned short* __restrict__ C) {          // g1 [NTOK][320]
    constexpr int BM = 128, BN = 64, BK = 32, K = 2048;
    __shared__ __align__(16) unsigned short As[2][BM][BK];
    __shared__ __align__(16) unsigned short Bs[2][BN][BK];
    constexpr int WN = BN / 2, FM = 4, FN = WN / 16;
    const int tid = threadIdx.x, wave = tid >> 6, lane = tid & 63;
    const int wr = wave >> 1, wc = wave & 1;
    const int lg = lane >> 4, lr = lane & 15;
    const int m0 = blockIdx.y * BM, n0 = blockIdx.x * BN;

    f32x4 acc[FM][FN] = {};
    const int ar = (tid * 16) >> 5, ac = (tid * 16) & 31;

    float4 a4[4];
    auto loadA = [&](int k0) {
        const float* src = A + (size_t)(m0 + ar) * K + k0 + ac;
#pragma unroll
        for (int i = 0; i < 4; ++i) a4[i] = *(const float4*)(src + i * 4);
    };
    auto writeA = [&](int buf) {
        unsigned int pk[8];
        const float* f = (const float*)a4;
#pragma unroll
        for (int i = 0; i < 8; ++i)
            asm("v_cvt_pk_bf16_f32 %0, %1, %2" : "=v"(pk[i]) : "v"(f[2 * i]), "v"(f[2 * i + 1]));
        *(uint4*)&As[buf][ar][ac]     = make_uint4(pk[0], pk[1], pk[2], pk[3]);
        *(uint4*)&As[buf][ar][ac + 8] = make_uint4(pk[4], pk[5], pk[6], pk[7]);
    };
    auto stageB = [&](int k0, int buf) {
        int e = tid * 8;
        GLOAD_LDS16(Bt + (size_t)(n0 + (e >> 5)) * K + k0 + (e & 31), &Bs[buf][0][0] + e);
    };

    loadA(0); stageB(0, 0); writeA(0);
    __syncthreads();
    constexpr int nk = K / BK;
    for (int t = 0; t < nk; ++t) {
        const int cur = t & 1;
        if (t + 1 < nk) { loadA((t + 1) * BK); stageB((t + 1) * BK, cur ^ 1); }
        short8 af[FM], bfr[FN];
#pragma unroll
        for (int i = 0; i < FM; i++) af[i] = *(const short8*)&As[cur][wr * 64 + i * 16 + lr][lg * 8];
#pragma unroll
        for (int j = 0; j < FN; j++) bfr[j] = *(const short8*)&Bs[cur][wc * WN + j * 16 + lr][lg * 8];
#pragma unroll
        for (int i = 0; i < FM; i++)
#pragma unroll
            for (int j = 0; j < FN; j++)
                acc[i][j] = __builtin_amdgcn_mfma_f32_16x16x32_bf16(af[i], bfr[j], acc[i][j], 0, 0, 0);
        if (t + 1 < nk) writeA(cur ^ 1);
        __syncthreads();
    }
#pragma unroll
    for (int i = 0; i < FM; i++)
#pragma unroll
        for (int j = 0; j < FN; j++)
#pragma unroll
            for (int r = 0; r < 4; r++) {
                int row = m0 + wr * 64 + i * 16 + lg * 4 + r;
                int col = n0 + wc * WN + j * 16 + lr;
                C[(size_t)row * 320 + col] = f2bf(acc[i][j][r]);
            }
}

// ---------------- out-proj: 128x256 deep-pipelined GEMM (T2+T3+T4+T5) ----------------
// C[4096][2048] f32 = attn[4096][2048]bf16 @ WeffT[2048][2048]^T. BK=64, 512 thr
// (8 waves 2Mx4N, 64x64/wave). 3 LDS buffers (144KB), depth-2 prefetch with counted
// vmcnt(12) (6 gload_lds/thread/tile), raw s_barrier (no vmcnt(0) drain in loop).
// Chunk-XOR swizzle: linear LDS dest + inverse-swizzled source + swizzled read.
__global__ __launch_bounds__(512, 2) void gemm_out_kernel(
    const unsigned short* __restrict__ Ag,     // attn [4096][2048]
    const unsigned short* __restrict__ Bg,     // WeffT [2048][2048]
    float* __restrict__ C) {
    __shared__ __align__(16) unsigned short As[3][128][64];
    __shared__ __align__(16) unsigned short Bs[3][256][64];
    const int tid = threadIdx.x, wave = tid >> 6, lane = tid & 63;
    const int wr = wave >> 2, wc = wave & 3;
    const int lg = lane >> 4, lr = lane & 15;
    int id = blockIdx.y * gridDim.x + blockIdx.x;      // grid (8, 32) = 256
    int swz = (id & 7) * 32 + (id >> 3);               // bijective XCD grouping
    const int n0 = (swz & 7) * 256;
    const int m0 = (swz >> 3) * 128;

    f32x4 acc[4][4] = {};

    auto STAGE = [&](int kt, int buf) {
        const int k0 = kt * 64;
#pragma unroll
        for (int it = 0; it < 2; ++it) {               // A: 128 rows x 8 chunks
            int cid = tid + it * 512;
            int row = cid >> 3, slot = cid & 7;
            int csrc = slot ^ (row & 7);
            GLOAD_LDS16(Ag + (size_t)(m0 + row) * 2048 + k0 + csrc * 8, &As[buf][0][0] + cid * 8);
        }
#pragma unroll
        for (int it = 0; it < 4; ++it) {               // B: 256 rows x 8 chunks
            int cid = tid + it * 512;
            int row = cid >> 3, slot = cid & 7;
            int csrc = slot ^ (row & 7);
            GLOAD_LDS16(Bg + (size_t)(n0 + row) * 2048 + k0 + csrc * 8, &Bs[buf][0][0] + cid * 8);
        }
    };
    auto compute = [&](int buf) {
#pragma unroll
        for (int ks = 0; ks < 2; ++ks) {
            const int ca = ((ks * 4 + lg) ^ (lr & 7)) * 8;   // swizzled read chunk
            short8 af[4], bfr[4];
#pragma unroll
            for (int i = 0; i < 4; i++) af[i] = *(const short8*)&As[buf][wr * 64 + i * 16 + lr][ca];
#pragma unroll
            for (int j = 0; j < 4; j++) bfr[j] = *(const short8*)&Bs[buf][wc * 64 + j * 16 + lr][ca];
            __builtin_amdgcn_s_setprio(1);
#pragma unroll
            for (int i = 0; i < 4; i++)
#pragma unroll
                for (int j = 0; j < 4; j++)
                    acc[i][j] = __builtin_amdgcn_mfma_f32_16x16x32_bf16(af[i], bfr[j], acc[i][j], 0, 0, 0);
            __builtin_amdgcn_s_setprio(0);
        }
    };

    STAGE(0, 0); STAGE(1, 1); STAGE(2, 2);             // 18 loads in flight
    for (int t = 0; t < 30; ++t) {
        asm volatile("s_waitcnt vmcnt(12)" ::: "memory");   // tile t landed (this wave)
        __builtin_amdgcn_s_barrier();                        // => landed for ALL waves
        asm volatile("" ::: "memory");
        compute(t % 3);
        asm volatile("" ::: "memory");
        __builtin_amdgcn_s_barrier();                        // all waves done reading buf t%3
        if (t < 29) STAGE(t + 3, t % 3);                     // overwrite; flies 3 tiles deep
    }
    asm volatile("s_waitcnt vmcnt(6)" ::: "memory");         // t=30
    __builtin_amdgcn_s_barrier();
    asm volatile("" ::: "memory");
    compute(0);
    asm volatile("" ::: "memory");
    __builtin_amdgcn_s_barrier();
    asm volatile("s_waitcnt vmcnt(0)" ::: "memory");         // t=31
    __builtin_amdgcn_s_barrier();
    asm volatile("" ::: "memory");
    compute(1);

#pragma unroll
    for (int i = 0; i < 4; i++)
#pragma unroll
        for (int j = 0; j < 4; j++)
#pragma unroll
            for (int r = 0; r < 4; r++) {
                int row = m0 + wr * 64 + i * 16 + lg * 4 + r;
                int col = n0 + wc * 64 + j * 16 + lr;
                C[(size_t)row * 2048 + col] = acc[i][j][r];
            }
}

// ---------------- flash attention v9: absorbed, 2 heads/block, split-pair balance ----------------
__global__ __launch_bounds__(512) void mla_attn_kernel(
    const unsigned short* __restrict__ q_all,   // [NTOK][3072]: per head [qtil(128)|qrope(64)]
    const unsigned short* __restrict__ g1,      // [NTOK][320]: ckv 0..127, roped k_r 256..319
    const unsigned short* __restrict__ ckv_t,   // [2][128][2048]
    unsigned short* __restrict__ attn_out,      // [NTOK][2048] (o_lat)
    unsigned short* __restrict__ partOb,        // [256 pair][2 side][128 q][128 d] bf16
    float* __restrict__ partL,
    float* __restrict__ partM) {
    __shared__ __align__(16) char smem[81920];
    auto Ks = (unsigned short (*)[64][192])smem;             // [2][64][192], chunk-swizzled
    auto Vs = (unsigned short (*)[128][64])(smem + 49152);   // [2][128][64], chunk-swizzled

    const int id = blockIdx.x;
    const int xcd = id & 7, loc = id >> 3;
    const int hp = 2 * xcd + (loc >> 4);        // head-pair 0..15
    const int s2 = loc & 15;
    const bool roleA = s2 < 8;
    const int qb = roleA ? s2 : s2 - 8;
    const int hiqb = 15 - qb, xsp = 15 - 2 * qb;
    const int b = hp >> 3;
    const int tid = threadIdx.x, wave = tid >> 6, lane = tid & 63;
    const int wg = wave & 3, hsel = wave >> 2;
    const int h = (hp & 7) * 2 + hsel;
    const int bh = b * 16 + h;
    const int pairIdx = bh * 8 + qb;
    const int ql = lane & 31, hb = lane >> 5;
    const int kvB = b * SS;
    const float sc2 = 0.12751744f;   // (1/sqrt(128)) * log2(e)
    const int xh = ql & 7;

    uint4 vreg[2];
    auto stageK = [&](int t, int bufi) {
#pragma unroll
        for (int it = 0; it < 3; ++it) {
            int cid = tid + it * 512;
            int r = cid / 24, s = cid - r * 24;
            int c = s ^ (r & 7);
            int col = (c < 16) ? c * 8 : 256 + (c - 16) * 8;
            GLOAD_LDS16(g1 + (size_t)(kvB + t * 64 + r) * 320 + col,
                        &Ks[bufi][0][0] + cid * 8);
        }
    };
    auto loadV = [&](int t) {
#pragma unroll
        for (int it = 0; it < 2; ++it) {
            int e = tid * 8 + it * 4096;
            vreg[it] = *(const uint4*)(ckv_t + ((size_t)b * 128 + (e >> 6)) * 2048 + t * 64 + (e & 63));
        }
    };
    auto writeV = [&](int bufi) {
#pragma unroll
        for (int it = 0; it < 2; ++it) {
            int e = tid * 8 + it * 4096;
            int d = e >> 6, j = (e & 63) >> 3;
            *(uint4*)&Vs[bufi][d][(j ^ (d & 7)) * 8] = vreg[it];
        }
    };

    auto run = [&](int q0, int t0, int cnt, bool direct, int side) {
        __syncthreads();
        const int q0w = q0 + wg * 32;
        const int qg = q0w + ql;

        short8 qf[12];
        {
            const unsigned short* qp = q_all + (size_t)(kvB + qg) * QSTR + h * HD2 + hb * 8;
#pragma unroll
            for (int ss = 0; ss < 12; ++ss) qf[ss] = *(const short8*)(qp + 16 * ss);
        }
        f32x16 o[4] = {};
        float m_raw = -3e38f, mb = 0.f, l_r = 0.f;

        stageK(t0, 0);
        loadV(t0);
        writeV(0);
        __syncthreads();

        for (int tt = 0; tt < cnt; ++tt) {
            const int t = t0 + tt;
            const int cur = tt & 1;
            if (tt + 1 < cnt) { stageK(t + 1, cur ^ 1); loadV(t + 1); }
            {
                f32x16 p0 = {}, p1 = {};
                __builtin_amdgcn_s_setprio(1);
#pragma unroll
                for (int ss = 0; ss < 12; ++ss) {
                    int pc = (((2 * ss + hb) ^ xh) << 3);
                    short8 k0 = *(const short8*)&Ks[cur][ql][pc];
                    short8 k1 = *(const short8*)&Ks[cur][32 + ql][pc];
                    p0 = __builtin_amdgcn_mfma_f32_32x32x16_bf16(k0, qf[ss], p0, 0, 0, 0);
                    p1 = __builtin_amdgcn_mfma_f32_32x32x16_bf16(k1, qf[ss], p1, 0, 0, 0);
                }
                __builtin_amdgcn_s_setprio(0);
                const int kv0 = t * 64;
                if (kv0 + 63 > q0w) {
#pragma unroll
                    for (int r = 0; r < 16; ++r) {
                        int kvg = kv0 + (r & 3) + 8 * (r >> 2) + 4 * hb;
                        if (kvg > qg) p0[r] = -3e38f;
                        if (kvg + 32 > qg) p1[r] = -3e38f;
                    }
                }
                float pm = -3e38f;
#pragma unroll
                for (int r = 0; r < 16; ++r) pm = fmaxf(pm, fmaxf(p0[r], p1[r]));
                pm = fmaxf(pm, __shfl_xor(pm, 32));
                if (__any(pm > m_raw + 64.f)) {   // defer-max (T13)
                    float mn = fmaxf(m_raw, pm);
                    float alpha = exp2f((m_raw - mn) * sc2);
                    m_raw = mn; mb = mn * sc2;
                    l_r *= alpha;
#pragma unroll
                    for (int dt = 0; dt < 4; ++dt)
#pragma unroll
                        for (int r = 0; r < 16; ++r) o[dt][r] *= alpha;
                }
                float ps = 0.f;
#pragma unroll
                for (int r = 0; r < 16; ++r) {
                    p0[r] = exp2f(__builtin_fmaf(p0[r], sc2, -mb));
                    p1[r] = exp2f(__builtin_fmaf(p1[r], sc2, -mb));
                    ps += p0[r] + p1[r];
                }
                l_r += ps;
                unsigned int pk0[8], pk1[8];
#pragma unroll
                for (int i = 0; i < 8; ++i) {
                    asm("v_cvt_pk_bf16_f32 %0, %1, %2" : "=v"(pk0[i]) : "v"(p0[2 * i]), "v"(p0[2 * i + 1]));
                    asm("v_cvt_pk_bf16_f32 %0, %1, %2" : "=v"(pk1[i]) : "v"(p1[2 * i]), "v"(p1[2 * i + 1]));
                }
                uint4 bfr[4];
#pragma unroll
                for (int sg = 0; sg < 2; ++sg) {
                    unsigned int x0 = pk0[4 * sg], y0 = pk0[4 * sg + 2];
                    asm volatile("v_permlane32_swap_b32 %0, %1" : "+v"(x0), "+v"(y0));
                    unsigned int x1 = pk0[4 * sg + 1], y1 = pk0[4 * sg + 3];
                    asm volatile("v_permlane32_swap_b32 %0, %1" : "+v"(x1), "+v"(y1));
                    bfr[sg] = make_uint4(x0, x1, y0, y1);
                    unsigned int x2 = pk1[4 * sg], y2 = pk1[4 * sg + 2];
                    asm volatile("v_permlane32_swap_b32 %0, %1" : "+v"(x2), "+v"(y2));
                    unsigned int x3 = pk1[4 * sg + 1], y3 = pk1[4 * sg + 3];
                    asm volatile("v_permlane32_swap_b32 %0, %1" : "+v"(x3), "+v"(y3));
                    bfr[2 + sg] = make_uint4(x2, x3, y2, y3);
                }
                __builtin_amdgcn_s_setprio(1);
#pragma unroll
                for (int ss = 0; ss < 4; ++ss) {
                    short8 pb = __builtin_bit_cast(short8, bfr[ss]);
                    int vc = (((2 * ss + hb) ^ xh) << 3);
#pragma unroll
                    for (int dt = 0; dt < 4; ++dt) {
                        short8 vf = *(const short8*)&Vs[cur][dt * 32 + ql][vc];
                        o[dt] = __builtin_amdgcn_mfma_f32_32x32x16_bf16(vf, pb, o[dt], 0, 0, 0);
                    }
                }
                __builtin_amdgcn_s_setprio(0);
            }
            if (tt + 1 < cnt) writeV(cur ^ 1);
            __syncthreads();
        }

        l_r += __shfl_xor(l_r, 32);
        if (direct) {
            float inv_l = 1.f / l_r;
            unsigned int* ep = (unsigned int*)smem + wave * 2176;
#pragma unroll
            for (int dt = 0; dt < 4; ++dt)
#pragma unroll
                for (int r = 0; r < 16; r += 2) {
                    float a = o[dt][r] * inv_l, c2 = o[dt][r + 1] * inv_l;
                    unsigned int pkv;
                    asm("v_cvt_pk_bf16_f32 %0, %1, %2" : "=v"(pkv) : "v"(a), "v"(c2));
                    ep[ql * 68 + dt * 16 + ((r & 3) >> 1) + 4 * (r >> 2) + 2 * hb] = pkv;
                }
#pragma unroll
            for (int it = 0; it < 8; ++it) {
                int qr = lane >> 1, ch = (lane & 1) * 8 + it;
                uint4 w = *(uint4*)&ep[qr * 68 + ch * 4];
                *(uint4*)(attn_out + (size_t)(kvB + q0w + qr) * 2048 + h * 128 + ch * 8) = w;
            }
        } else {
            float* sW = (float*)smem + wg * 4224;
            const size_t pb2 = ((size_t)pairIdx * 2 + side);
#pragma unroll
            for (int pass = 0; pass < 2; ++pass) {
                if (pass == 1) __syncthreads();
                if (hsel == pass) {
#pragma unroll
                    for (int dt = 0; dt < 4; ++dt)
#pragma unroll
                        for (int r = 0; r < 16; ++r)
                            sW[ql * 132 + dt * 32 + (r & 3) + 8 * (r >> 2) + 4 * hb] = o[dt][r];
                    int q = lane >> 1, half = lane & 1;
                    const float* src = sW + q * 132 + half * 64;
                    unsigned int* dst = (unsigned int*)(partOb + pb2 * 16384 + ((size_t)(wg * 32 + q)) * 128 + half * 64);
#pragma unroll
                    for (int j = 0; j < 64; j += 4) {
                        float4 f = *(const float4*)(src + j);
                        unsigned int d0, d1;
                        asm("v_cvt_pk_bf16_f32 %0, %1, %2" : "=v"(d0) : "v"(f.x), "v"(f.y));
                        asm("v_cvt_pk_bf16_f32 %0, %1, %2" : "=v"(d1) : "v"(f.z), "v"(f.w));
                        *(uint2*)(dst + (j >> 1)) = make_uint2(d0, d1);
                    }
                    if (hb == 0) {
                        partL[pb2 * 128 + wg * 32 + ql] = l_r;
                        partM[pb2 * 128 + wg * 32 + ql] = m_raw;
                    }
                }
            }
        }
    };

    if (roleA) {
        run(qb * 128, 0, 2 * qb + 2, true, 0);
        run(hiqb * 128, 0, xsp, false, 0);
    } else {
        run(hiqb * 128, xsp, 17, false, 1);
    }
}

// merge the two partials of each hi q-tile (bf16 partO)
__global__ __launch_bounds__(256) void merge_kernel(
    const unsigned short* __restrict__ partOb, const float* __restrict__ partL,
    const float* __restrict__ partM, unsigned short* __restrict__ attn_out) {
    __shared__ float sA[128], sB[128], sI[128];
    const int p = blockIdx.x, tid = threadIdx.x;
    const int bh = p >> 3, qb = p & 7;
    const int b = bh >> 4, h = bh & 15;
    const int q0 = (15 - qb) * 128;
    const float sc2 = 0.12751744f;
    if (tid < 128) {
        float mA = partM[(size_t)(p * 2) * 128 + tid];
        float mB = partM[(size_t)(p * 2 + 1) * 128 + tid];
        float mM = fmaxf(mA, mB);
        float aA = exp2f((mA - mM) * sc2), aB = exp2f((mB - mM) * sc2);
        float lT = aA * partL[(size_t)(p * 2) * 128 + tid] + aB * partL[(size_t)(p * 2 + 1) * 128 + tid];
        sA[tid] = aA; sB[tid] = aB; sI[tid] = 1.f / lT;
    }
    __syncthreads();
    const int q = tid >> 1, half = tid & 1;
    const float aA = sA[q], aB = sB[q], inv = sI[q];
    const unsigned short* oA = partOb + (size_t)(p * 2) * 16384 + q * 128 + half * 64;
    const unsigned short* oB = partOb + (size_t)(p * 2 + 1) * 16384 + q * 128 + half * 64;
    unsigned short* dst = attn_out + (size_t)(b * SS + q0 + q) * 2048 + h * 128 + half * 64;
#pragma unroll
    for (int j = 0; j < 64; j += 4) {
        ushort4 ua = *(const ushort4*)(oA + j);
        ushort4 ub = *(const ushort4*)(oB + j);
        ushort4 u;
        u.x = f2bf((aA * bf2f(ua.x) + aB * bf2f(ub.x)) * inv);
        u.y = f2bf((aA * bf2f(ua.y) + aB * bf2f(ub.y)) * inv);
        u.z = f2bf((aA * bf2f(ua.z) + aB * bf2f(ub.z)) * inv);
        u.w = f2bf((aA * bf2f(ua.w) + aB * bf2f(ub.w)) * inv);
        *(ushort4*)(dst + j) = u;
    }
}

// ---------------- launcher ----------------

extern "C" void kernel_launch(void* const* d_in, const int* in_sizes, int n_in,
                              void* d_out, int out_size, void* d_ws, size_t ws_size,
                              hipStream_t stream) {
    const float* x     = (const float*)d_in[0];
    const float* W_dkv = (const float*)d_in[1];
    const float* W_dq  = (const float*)d_in[2];
    const float* W_kr  = (const float*)d_in[3];
    const float* W_qc  = (const float*)d_in[4];
    const float* W_qr  = (const float*)d_in[5];
    const float* W_uk  = (const float*)d_in[6];
    const float* W_uv  = (const float*)d_in[7];
    const float* W_o   = (const float*)d_in[8];
    float* out = (float*)d_out;

    size_t off = 0;
    auto alloc = [&](size_t bytes) {
        void* p = (char*)d_ws + off;
        off = (off + bytes + 255) & ~(size_t)255;
        return p;
    };
    unsigned short* WcatT = (unsigned short*)alloc((size_t)320 * 2048 * 2);
    unsigned short* Wq2T  = (unsigned short*)alloc((size_t)3072 * 128 * 2);
    unsigned short* WqcB  = (unsigned short*)alloc((size_t)16 * 128 * 64 * 2);
    unsigned short* WukB  = (unsigned short*)alloc((size_t)16 * 128 * 64 * 2);
    unsigned short* WuvB  = (unsigned short*)alloc((size_t)16 * 128 * 128 * 2);
    unsigned short* WoT   = (unsigned short*)alloc((size_t)2048 * 2048 * 2);
    unsigned short* WeffT = (unsigned short*)alloc((size_t)2048 * 2048 * 2);
    unsigned short* g1    = (unsigned short*)alloc((size_t)NTOK * 320 * 2);
    unsigned short* q_all = (unsigned short*)alloc((size_t)NTOK * QSTR * 2);
    unsigned short* ckv_t = (unsigned short*)alloc((size_t)2 * 128 * 2048 * 2);
    unsigned short* attn  = (unsigned short*)alloc((size_t)NTOK * 2048 * 2);
    float2* rope_tab      = (float2*)alloc((size_t)SS * 32 * sizeof(float2));
    unsigned short* partOb= (unsigned short*)alloc((size_t)256 * 2 * 16384 * 2);
    float* partL          = (float*)alloc((size_t)256 * 2 * 128 * 4);
    float* partM          = (float*)alloc((size_t)256 * 2 * 128 * 4);

    // 1: layouts + bf16 copies + rope table
    prep_kernel<<<6400, 256, 0, stream>>>(W_dkv, W_dq, W_kr, W_qc, W_qr, W_uk, W_uv, W_o,
                                          WcatT, Wq2T, WqcB, WukB, WuvB, WoT, rope_tab);
    // 2: absorbed-weight precomputes
    wqk_kernel<<<16, 256, 0, stream>>>(WqcB, WukB, Wq2T);
    weff_kernel<<<dim3(16, 16), 256, 0, stream>>>(WoT, WuvB, WeffT);
    // 3: latent GEMM (f32 A, conversion folded)
    gemm_lat_kernel<<<dim3(5, 32), 256, 0, stream>>>(x, WcatT, g1);
    // 4: c_kv transpose
    ckvt_kernel<<<dim3(32, 2, 2), 256, 0, stream>>>(g1, ckv_t);
    // 5: absorbed q projection (q_tilde | q_rope), K=128
    gemm_bf16_kernel<128, unsigned short, false><<<dim3(24, 32), 256, 0, stream>>>(
        g1 + 128, 320, Wq2T, 128, q_all, QSTR, NTOK, QSTR, 128);
    // 6: both ropes
    rope_all_kernel<<<512 + 8192, 256, 0, stream>>>(g1, q_all, rope_tab);
    // 7: attention (2 heads/block, split-pair balanced) + merge
    mla_attn_kernel<<<256, 512, 0, stream>>>(q_all, g1, ckv_t, attn, partOb, partL, partM);
    merge_kernel<<<256, 256, 0, stream>>>(partOb, partL, partM, attn);
    // 8: output projection with W_eff -> fp32 (deep-pipelined)
    gemm_out_kernel<<<dim3(8, 32), 512, 0, stream>>>(attn, WeffT, out);
}